// Round 8
// baseline (20297.543 us; speedup 1.0000x reference)
//
#include <hip/hip_runtime.h>
#include <stdint.h>

// Seq2Seq (bi-LSTM encoder + greedy LSTM decoder), MI355X gfx950.
// v8: split-K classifier for 2 blocks/CU occupancy.
//   R7 post-mortem: kernel-chain killed the ~8.6ms of grid-barrier cost
//   (16.25->7.61ms). Remaining budget est: k_cls 63x~60us = 3.8ms dominant;
//   its pipes (HBM 21us, VALU 14us, LDS ~12us, VMEM issue ~14us) don't
//   overlap at 16 waves/CU (1 block/CU, 128KB LDS). v8: k_cls splits K in
//   half -> cH 66KB -> 2 blocks/CU (32 waves/CU); partials (no bias) to
//   pbuf (reuses decode-dead Xg region); new k_red sums halves + bias,
//   LDS-transposes for coalesced out writes, does argmax.
//
// B=32 S=128 T=64 V=32000 E=512 H=512 (4H=2048 gates per cell)

#define NT 1024
#define NBLK 256

constexpr int HSTR = 580;    // enc h-stage LDS row stride (512 + pad, %32==4)
constexpr int XSTR = 1156;   // dec [x|h]-stage stride (1024 + pad, %32==4)
constexpr unsigned LDS_ENC = 78336;    // (32*580 + 512 + 512) floats
constexpr unsigned LDS_CELL = 150016;  // (32*1156 + 512) floats
constexpr unsigned LDS_CLS = 66048;    // cH [32][129] float4

// workspace layout (bytes)
constexpr size_t OFF_AMAX  = 0;                     // 63*32 u64 = 16128
constexpr size_t OFF_XG    = 17408;                 // Xg (encoder) / pbuf (decode) 
constexpr size_t OFF_HENC  = OFF_XG + 67108864ULL;  // 2buf*2dir*32*512 f32 = 262144
constexpr size_t OFF_HCAT  = OFF_HENC + 262144ULL;  // 2buf*32*1024 f32 = 262144
constexpr size_t OFF_CST   = OFF_HCAT + 262144ULL;  // 2dir*32*512 f32 = 131072

__device__ __forceinline__ float sigm(float x) {
  if (x >= 0.f) return 1.f / (1.f + expf(-x));
  float e = expf(x);
  return e / (1.f + e);
}

__device__ __forceinline__ void fma4(const float4& w, const float4& h, float4& a) {
  a.x = fmaf(w.x, h.x, a.x);
  a.y = fmaf(w.y, h.y, a.y);
  a.z = fmaf(w.z, h.z, a.z);
  a.w = fmaf(w.w, h.w, a.w);
}

__device__ __forceinline__ float hsum4(const float4& a) {
  return (a.x + a.y) + (a.z + a.w);
}

__device__ __forceinline__ float dot4(const float4& w, const float4& h, float acc) {
  return fmaf(w.x, h.x, fmaf(w.y, h.y, fmaf(w.z, h.z, fmaf(w.w, h.w, acc))));
}

__device__ __forceinline__ unsigned long long lgkey(float lg, int vr) {
  unsigned u = __float_as_uint(lg);
  u = (u & 0x80000000u) ? ~u : (u | 0x80000000u);
  return ((unsigned long long)u << 32) | (0xFFFFFFFFu - (unsigned)vr);
}

// ---------------- K0: Xg = emb(src) @ wih^T + bih + bhh; init h_enc, out ----
__global__ __launch_bounds__(NT) void k_xg(
    const int* __restrict__ src, const float* __restrict__ enc_emb,
    const float* __restrict__ ewih_f, const float* __restrict__ ebih_f,
    const float* __restrict__ ebhh_f,
    const float* __restrict__ ewih_r, const float* __restrict__ ebih_r,
    const float* __restrict__ ebhh_r,
    float* __restrict__ Xg, float* __restrict__ h_enc, float* __restrict__ out) {
  extern __shared__ float smem[];
  const int tid = threadIdx.x;
  const int bid = blockIdx.x;
  const int d  = bid >> 7;
  const int u0 = (bid & 127) << 2;

  float* hL  = smem;               // [32][HSTR]

  const int rgE = tid >> 7;
  const int bpE = (tid >> 4) & 7;
  const int ksE = tid & 15;
  const int r0E = rgE * 2, r1E = r0E + 1;
  const int growE0 = (r0E & 3) * 512 + u0 + (r0E >> 2);
  const int growE1 = (r1E & 3) * 512 + u0 + (r1E >> 2);

  const float* ewih = d ? ewih_r : ewih_f;
  const float* ebih = d ? ebih_r : ebih_f;
  const float* ebhh = d ? ebhh_r : ebhh_f;

  float4 wA[8], wB[8];
#pragma unroll
  for (int i4 = 0; i4 < 8; ++i4) {
    wA[i4] = *(const float4*)(ewih + (size_t)growE0 * 512 + ksE * 32 + i4 * 4);
    wB[i4] = *(const float4*)(ewih + (size_t)growE1 * 512 + ksE * 32 + i4 * 4);
  }
  const float biasA = ebih[growE0] + ebhh[growE0];
  const float biasB = ebih[growE1] + ebhh[growE1];

  for (int t = 0; t < 128; ++t) {
    {
      int b = tid >> 5, i = tid & 31;
      int tok = src[b * 128 + t];
      const float* row = enc_emb + (size_t)tok * 512;
#pragma unroll
      for (int q = 0; q < 4; ++q) {
        int k = (i + 32 * q) * 4;
        float4 v = *(const float4*)(row + k);
        int pc = k + ((k >> 5) << 2);
        *(float4*)(hL + b * HSTR + pc) = v;
      }
    }
    __syncthreads();
    for (int gi = 0; gi < 4; ++gi) {
      int b = bpE * 4 + gi;
      const float* hb = hL + b * HSTR + ksE * 36;
      float4 a0 = {0, 0, 0, 0}, a1 = {0, 0, 0, 0};
#pragma unroll
      for (int i4 = 0; i4 < 8; ++i4) {
        float4 h4 = *(const float4*)(hb + i4 * 4);
        fma4(wA[i4], h4, a0);
        fma4(wB[i4], h4, a1);
      }
      float s0 = hsum4(a0), s1 = hsum4(a1);
#pragma unroll
      for (int m = 1; m <= 8; m <<= 1) {
        s0 += __shfl_xor(s0, m, 64);
        s1 += __shfl_xor(s1, m, 64);
      }
      if (ksE == 0) {
        float* xgp = Xg + ((size_t)bid << 16) + t * 512 + b * 16;
        xgp[r0E] = s0 + biasA;
        xgp[r1E] = s1 + biasB;
      }
    }
    __syncthreads();
  }

  if (tid < 128) {
    int b = tid & 31, j = tid >> 5;
    h_enc[((0 * 2 + d) * 32 + b) * 512 + u0 + j] = 0.f;
  }
  for (int i = tid; i < 4000; i += NT) {
    int b = i & 31, vv = i >> 5;  // vv < 125
    out[(size_t)b * 64 * 32000 + bid * 125 + vv] = 0.f;
  }
}

// ---------------- K_enc: one bi-LSTM encoder time step ----------------
__global__ __launch_bounds__(NT) void k_enc(
    const float* __restrict__ ewhh_f, const float* __restrict__ ewhh_r,
    const float* __restrict__ Xg, float* __restrict__ h_enc,
    float* __restrict__ hcat, float* __restrict__ c_st, int s) {
  extern __shared__ float smem[];
  const int tid = threadIdx.x;
  const int bid = blockIdx.x;
  const int d  = bid >> 7;
  const int u0 = (bid & 127) << 2;
  const int cur = s & 1;
  const int td = d ? (127 - s) : s;

  float* hL  = smem;               // [32][HSTR]
  float* XgL = smem + 32 * HSTR;   // [32*16]
  float* gL  = XgL + 512;          // [32*16]

  const int rgE = tid >> 7;
  const int bpE = (tid >> 4) & 7;
  const int ksE = tid & 15;
  const int r0E = rgE * 2, r1E = r0E + 1;
  const int growE0 = (r0E & 3) * 512 + u0 + (r0E >> 2);
  const int growE1 = (r1E & 3) * 512 + u0 + (r1E >> 2);

  const float* ewhh = d ? ewhh_r : ewhh_f;

  float4 wA[8], wB[8];
#pragma unroll
  for (int i4 = 0; i4 < 8; ++i4) {
    wA[i4] = *(const float4*)(ewhh + (size_t)growE0 * 512 + ksE * 32 + i4 * 4);
    wB[i4] = *(const float4*)(ewhh + (size_t)growE1 * 512 + ksE * 32 + i4 * 4);
  }

  {
    int b = tid >> 5, i = tid & 31;
    const float* hr = h_enc + ((size_t)(cur * 2 + d) * 32 + b) * 512;
#pragma unroll
    for (int q = 0; q < 4; ++q) {
      int k = (i + 32 * q) * 4;
      float4 v = *(const float4*)(hr + k);
      int pc = k + ((k >> 5) << 2);
      *(float4*)(hL + b * HSTR + pc) = v;
    }
    if (tid < 128) {
      ((float4*)XgL)[tid] =
          *(const float4*)(Xg + ((size_t)bid << 16) + td * 512 + tid * 4);
    }
  }
  __syncthreads();
  for (int gi = 0; gi < 4; ++gi) {
    int b = bpE * 4 + gi;
    const float* hb = hL + b * HSTR + ksE * 36;
    float4 a0 = {0, 0, 0, 0}, a1 = {0, 0, 0, 0};
#pragma unroll
    for (int i4 = 0; i4 < 8; ++i4) {
      float4 h4 = *(const float4*)(hb + i4 * 4);
      fma4(wA[i4], h4, a0);
      fma4(wB[i4], h4, a1);
    }
    float s0 = hsum4(a0), s1 = hsum4(a1);
#pragma unroll
    for (int m = 1; m <= 8; m <<= 1) {
      s0 += __shfl_xor(s0, m, 64);
      s1 += __shfl_xor(s1, m, 64);
    }
    if (ksE == 0) {
      gL[b * 16 + r0E] = s0 + XgL[b * 16 + r0E];
      gL[b * 16 + r1E] = s1 + XgL[b * 16 + r1E];
    }
  }
  __syncthreads();
  if (tid < 128) {
    int b = tid & 31, j = tid >> 5;
    float g_i = gL[b * 16 + (j << 2) + 0];
    float g_f = gL[b * 16 + (j << 2) + 1];
    float g_g = gL[b * 16 + (j << 2) + 2];
    float g_o = gL[b * 16 + (j << 2) + 3];
    float c = (s == 0) ? 0.f : c_st[(d * 32 + b) * 512 + u0 + j];
    c = sigm(g_f) * c + sigm(g_i) * tanhf(g_g);
    float h = sigm(g_o) * tanhf(c);
    c_st[(d * 32 + b) * 512 + u0 + j] = c;
    h_enc[(((cur ^ 1) * 2 + d) * 32 + b) * 512 + u0 + j] = h;
    if (s == 127) hcat[b * 1024 + d * 512 + u0 + j] = h;  // buf 0
  }
}

// ---------------- K_cell: one decoder LSTM step (both dirs) ----------------
__global__ __launch_bounds__(NT) void k_cell(
    const int* __restrict__ tgt, const float* __restrict__ dec_emb,
    const float* __restrict__ dwih_f, const float* __restrict__ dwhh_f,
    const float* __restrict__ dbih_f, const float* __restrict__ dbhh_f,
    const float* __restrict__ dwih_r, const float* __restrict__ dwhh_r,
    const float* __restrict__ dbih_r, const float* __restrict__ dbhh_r,
    float* __restrict__ hcat, float* __restrict__ c_st,
    const unsigned long long* __restrict__ amax, int t) {
  extern __shared__ float smem[];
  const int tid = threadIdx.x;
  const int bid = blockIdx.x;
  const int d  = bid >> 7;
  const int u0 = (bid & 127) << 2;
  const int p = t & 1;

  float* xhL = smem;               // [32][XSTR]
  float* gLd = smem + 32 * XSTR;   // [32*16]

  const int rgD = tid >> 7;
  const int bpD = (tid >> 5) & 3;
  const int ksD = tid & 31;
  const int r0D = rgD * 2, r1D = r0D + 1;
  const int growD0 = (r0D & 3) * 512 + u0 + (r0D >> 2);
  const int growD1 = (r1D & 3) * 512 + u0 + (r1D >> 2);

  const float* dwih = d ? dwih_r : dwih_f;
  const float* dwhh = d ? dwhh_r : dwhh_f;
  const float* dbih = d ? dbih_r : dbih_f;
  const float* dbhh = d ? dbhh_r : dbhh_f;

  {
    int b = tid >> 5, i = tid & 31;
    int tok;
    if (t == 0) {
      tok = tgt[b * 64];
    } else {
      unsigned long long kv = amax[(t - 1) * 32 + b];
      tok = (int)(0xFFFFFFFFu - (unsigned)(kv & 0xFFFFFFFFull));
    }
    const float* xr = dec_emb + (size_t)tok * 512;
    const float* hr = hcat + (size_t)p * 32768 + b * 1024 + d * 512;
#pragma unroll
    for (int q = 0; q < 4; ++q) {
      int k = (i + 32 * q) * 4;
      float4 v = *(const float4*)(xr + k);
      int pc = k + ((k >> 5) << 2);
      *(float4*)(xhL + b * XSTR + pc) = v;
    }
#pragma unroll
    for (int q = 0; q < 4; ++q) {
      int k = (i + 32 * q) * 4;
      float4 v = *(const float4*)(hr + k);
      int c2 = 512 + k;
      int pc = c2 + ((c2 >> 5) << 2);
      *(float4*)(xhL + b * XSTR + pc) = v;
    }
  }
  float4 wA[8], wB[8];
  {
    const float* s0p = (ksD < 16) ? (dwih + (size_t)growD0 * 512 + ksD * 32)
                                  : (dwhh + (size_t)growD0 * 512 + (ksD - 16) * 32);
    const float* s1p = (ksD < 16) ? (dwih + (size_t)growD1 * 512 + ksD * 32)
                                  : (dwhh + (size_t)growD1 * 512 + (ksD - 16) * 32);
#pragma unroll
    for (int i4 = 0; i4 < 8; ++i4) {
      wA[i4] = *(const float4*)(s0p + i4 * 4);
      wB[i4] = *(const float4*)(s1p + i4 * 4);
    }
  }
  const float biasA = dbih[growD0] + dbhh[growD0];
  const float biasB = dbih[growD1] + dbhh[growD1];
  __syncthreads();
  for (int gi = 0; gi < 8; ++gi) {
    int b = bpD * 8 + gi;
    const float* hb = xhL + b * XSTR + ksD * 36;
    float4 a0 = {0, 0, 0, 0}, a1 = {0, 0, 0, 0};
#pragma unroll
    for (int i4 = 0; i4 < 8; ++i4) {
      float4 h4 = *(const float4*)(hb + i4 * 4);
      fma4(wA[i4], h4, a0);
      fma4(wB[i4], h4, a1);
    }
    float s0 = hsum4(a0), s1 = hsum4(a1);
#pragma unroll
    for (int m = 1; m <= 16; m <<= 1) {
      s0 += __shfl_xor(s0, m, 64);
      s1 += __shfl_xor(s1, m, 64);
    }
    if (ksD == 0) {
      gLd[b * 16 + r0D] = s0 + biasA;
      gLd[b * 16 + r1D] = s1 + biasB;
    }
  }
  __syncthreads();
  if (tid < 128) {
    int b = tid & 31, j = tid >> 5;
    float g_i = gLd[b * 16 + (j << 2) + 0];
    float g_f = gLd[b * 16 + (j << 2) + 1];
    float g_g = gLd[b * 16 + (j << 2) + 2];
    float g_o = gLd[b * 16 + (j << 2) + 3];
    float c = c_st[(d * 32 + b) * 512 + u0 + j];
    c = sigm(g_f) * c + sigm(g_i) * tanhf(g_g);
    float h = sigm(g_o) * tanhf(c);
    c_st[(d * 32 + b) * 512 + u0 + j] = c;
    hcat[(size_t)(p ^ 1) * 32768 + b * 1024 + d * 512 + u0 + j] = h;
  }
}

// ---------------- K_cls: split-K partial classifier ----------------
// grid 512 = (g row-group [0,256)) x (kh k-half {0,1}); 2 blocks/CU.
// Writes bias-free partials to pbuf[(g*2+kh)][row 128][b 32].
__global__ __launch_bounds__(NT, 8) void k_cls(
    const float* __restrict__ cls_w, const float* __restrict__ hcat,
    float* __restrict__ pbuf, int t) {
  extern __shared__ float smem[];  // cH: [32][129] float4 = 66048 B
  const int tid = threadIdx.x;
  const int g  = blockIdx.x & 255;
  const int kh = blockIdx.x >> 8;
  const int p = t & 1;

  {  // stage this k-half of h
    const float4* hr4 = (const float4*)(hcat + (size_t)(p ^ 1) * 32768);
    float4* cH4w = (float4*)smem;
#pragma unroll
    for (int q = 0; q < 4; ++q) {
      int f = tid + q * 1024;        // [0,4096)
      int b = f >> 7, k4 = f & 127;
      cH4w[b * 129 + k4] = hr4[b * 256 + kh * 128 + k4];
    }
  }
  __syncthreads();
  {
    const int lane = tid & 63;
    const int widu = __builtin_amdgcn_readfirstlane(tid >> 6);
    const int kc = lane & 3;
    const int bg = lane >> 2;
    const int b0 = bg * 2, b1 = b0 + 1;
    const float4* cH4 = (const float4*)smem;

    const float* wr[8];
#pragma unroll
    for (int r = 0; r < 8; ++r) {
      int lr = widu * 8 + r;
      lr = lr > 124 ? 124 : lr;
      wr[r] = cls_w + (size_t)(g * 125 + lr) * 1024 + kh * 512;
    }

    float acc[16];
#pragma unroll
    for (int i = 0; i < 16; ++i) acc[i] = 0.f;

    const float4* hp0 = cH4 + b0 * 129 + kc;
    const float4* hp1 = cH4 + b1 * 129 + kc;
    const int fo = kc * 4;
#pragma unroll 2
    for (int q = 0; q < 32; ++q) {
      const int ko = q * 16 + fo;
      float4 w0 = *(const float4*)(wr[0] + ko);
      float4 w1 = *(const float4*)(wr[1] + ko);
      float4 w2 = *(const float4*)(wr[2] + ko);
      float4 w3 = *(const float4*)(wr[3] + ko);
      float4 w4 = *(const float4*)(wr[4] + ko);
      float4 w5 = *(const float4*)(wr[5] + ko);
      float4 w6 = *(const float4*)(wr[6] + ko);
      float4 w7 = *(const float4*)(wr[7] + ko);
      float4 h40 = hp0[q * 4];
      float4 h41 = hp1[q * 4];
      acc[0]  = dot4(w0, h40, acc[0]);   acc[1]  = dot4(w0, h41, acc[1]);
      acc[2]  = dot4(w1, h40, acc[2]);   acc[3]  = dot4(w1, h41, acc[3]);
      acc[4]  = dot4(w2, h40, acc[4]);   acc[5]  = dot4(w2, h41, acc[5]);
      acc[6]  = dot4(w3, h40, acc[6]);   acc[7]  = dot4(w3, h41, acc[7]);
      acc[8]  = dot4(w4, h40, acc[8]);   acc[9]  = dot4(w4, h41, acc[9]);
      acc[10] = dot4(w5, h40, acc[10]);  acc[11] = dot4(w5, h41, acc[11]);
      acc[12] = dot4(w6, h40, acc[12]);  acc[13] = dot4(w6, h41, acc[13]);
      acc[14] = dot4(w7, h40, acc[14]);  acc[15] = dot4(w7, h41, acc[15]);
    }

    // butterfly-sum over the 4 kc lanes (masks 1,2)
#pragma unroll
    for (int i = 0; i < 16; ++i) {
      acc[i] += __shfl_xor(acc[i], 1, 64);
      acc[i] += __shfl_xor(acc[i], 2, 64);
    }

    // static row-select tree: lane kc keeps rows rA=kc, rB=kc+4
    float sA0, sA1, sB0, sB1;
    {
      float t0 = (kc & 1) ? acc[2]  : acc[0];
      float t1 = (kc & 1) ? acc[6]  : acc[4];
      sA0 = (kc & 2) ? t1 : t0;
      float u0v = (kc & 1) ? acc[3]  : acc[1];
      float u1v = (kc & 1) ? acc[7]  : acc[5];
      sA1 = (kc & 2) ? u1v : u0v;
      float v0v = (kc & 1) ? acc[10] : acc[8];
      float v1v = (kc & 1) ? acc[14] : acc[12];
      sB0 = (kc & 2) ? v1v : v0v;
      float w0v = (kc & 1) ? acc[11] : acc[9];
      float w1v = (kc & 1) ? acc[15] : acc[13];
      sB1 = (kc & 2) ? w1v : w0v;
    }

    const int lrA = widu * 8 + kc;       // <= 123, always valid
    const int lrB = lrA + 4;             // up to 127; >=125 invalid
    float* pb = pbuf + ((size_t)(g * 2 + kh)) * 4096;
    pb[lrA * 32 + b0] = sA0;
    pb[lrA * 32 + b1] = sA1;
    if (lrB < 125) {
      pb[lrB * 32 + b0] = sB0;
      pb[lrB * 32 + b1] = sB1;
    }
  }
}

// ---------------- K_red: sum halves + bias, out writeback, argmax ----------
__global__ __launch_bounds__(NT) void k_red(
    const float* __restrict__ cls_b, const float* __restrict__ pbuf,
    float* __restrict__ out, unsigned long long* __restrict__ amax, int t) {
  __shared__ float trans[32 * 129];
  __shared__ unsigned long long amaxL[32];
  const int tid = threadIdx.x;
  const int g = blockIdx.x;

  if (tid < 32) amaxL[tid] = 0ull;
  __syncthreads();
  {
    const int b = tid & 31, rq = tid >> 5;   // rq in [0,32)
    const float* p0 = pbuf + (size_t)(g * 2 + 0) * 4096;
    const float* p1 = pbuf + (size_t)(g * 2 + 1) * 4096;
    unsigned long long bk = 0ull;
#pragma unroll
    for (int jj = 0; jj < 4; ++jj) {
      int r = rq * 4 + jj;
      if (r < 125) {
        int vr = g * 125 + r;
        float lg = p0[r * 32 + b] + p1[r * 32 + b] + cls_b[vr];
        trans[b * 129 + r] = lg;
        unsigned long long k = lgkey(lg, vr);
        bk = k > bk ? k : bk;
      }
    }
    // lanes l and l^32 share b (tid = rq*32+b) -> combine, then LDS atomic
    unsigned long long o = __shfl_xor(bk, 32, 64);
    bk = o > bk ? o : bk;
    if ((tid & 63) < 32) atomicMax(&amaxL[b], bk);
  }
  __syncthreads();
#pragma unroll
  for (int it = 0; it < 4; ++it) {
    int idx = tid + it * 1024;              // [0,4096)
    int b = idx >> 7, j = idx & 127;
    if (j < 125)
      out[((size_t)b * 64 + (t + 1)) * 32000 + g * 125 + j] = trans[b * 129 + j];
  }
  if (tid < 32) atomicMax(&amax[t * 32 + tid], amaxL[tid]);
}

extern "C" void kernel_launch(void* const* d_in, const int* in_sizes, int n_in,
                              void* d_out, int out_size, void* d_ws, size_t ws_size,
                              hipStream_t stream) {
  (void)in_sizes; (void)n_in; (void)out_size; (void)ws_size;
  const int*   src     = (const int*)d_in[0];
  const int*   tgt     = (const int*)d_in[1];
  const float* enc_emb = (const float*)d_in[2];
  const float* dec_emb = (const float*)d_in[3];
  const float* ewih_f  = (const float*)d_in[4];
  const float* ewhh_f  = (const float*)d_in[5];
  const float* ebih_f  = (const float*)d_in[6];
  const float* ebhh_f  = (const float*)d_in[7];
  const float* ewih_r  = (const float*)d_in[8];
  const float* ewhh_r  = (const float*)d_in[9];
  const float* ebih_r  = (const float*)d_in[10];
  const float* ebhh_r  = (const float*)d_in[11];
  const float* dwih_f  = (const float*)d_in[12];
  const float* dwhh_f  = (const float*)d_in[13];
  const float* dbih_f  = (const float*)d_in[14];
  const float* dbhh_f  = (const float*)d_in[15];
  const float* dwih_r  = (const float*)d_in[16];
  const float* dwhh_r  = (const float*)d_in[17];
  const float* dbih_r  = (const float*)d_in[18];
  const float* dbhh_r  = (const float*)d_in[19];
  const float* cls_w   = (const float*)d_in[20];
  const float* cls_b   = (const float*)d_in[21];

  char* ws = (char*)d_ws;
  unsigned long long* amax = (unsigned long long*)(ws + OFF_AMAX);
  float* Xg                = (float*)(ws + OFF_XG);
  float* pbuf              = (float*)(ws + OFF_XG);  // Xg dead during decode
  float* h_enc             = (float*)(ws + OFF_HENC);
  float* hcat              = (float*)(ws + OFF_HCAT);
  float* c_st              = (float*)(ws + OFF_CST);
  float* out               = (float*)d_out;

  // reset argmax slots (monotone atomicMax needs zeros each call)
  hipMemsetAsync(d_ws, 0, OFF_XG, stream);

  hipFuncSetAttribute((const void*)k_xg,
                      hipFuncAttributeMaxDynamicSharedMemorySize, LDS_ENC);
  hipFuncSetAttribute((const void*)k_enc,
                      hipFuncAttributeMaxDynamicSharedMemorySize, LDS_ENC);
  hipFuncSetAttribute((const void*)k_cell,
                      hipFuncAttributeMaxDynamicSharedMemorySize, LDS_CELL);
  hipFuncSetAttribute((const void*)k_cls,
                      hipFuncAttributeMaxDynamicSharedMemorySize, LDS_CLS);

  hipLaunchKernelGGL(k_xg, dim3(NBLK), dim3(NT), LDS_ENC, stream,
                     src, enc_emb, ewih_f, ebih_f, ebhh_f,
                     ewih_r, ebih_r, ebhh_r, Xg, h_enc, out);

  for (int s = 0; s < 128; ++s) {
    hipLaunchKernelGGL(k_enc, dim3(NBLK), dim3(NT), LDS_ENC, stream,
                       ewhh_f, ewhh_r, Xg, h_enc, hcat, c_st, s);
  }

  for (int t = 0; t < 63; ++t) {
    hipLaunchKernelGGL(k_cell, dim3(NBLK), dim3(NT), LDS_CELL, stream,
                       tgt, dec_emb,
                       dwih_f, dwhh_f, dbih_f, dbhh_f,
                       dwih_r, dwhh_r, dbih_r, dbhh_r,
                       hcat, c_st, amax, t);
    hipLaunchKernelGGL(k_cls, dim3(NBLK * 2), dim3(NT), LDS_CLS, stream,
                       cls_w, hcat, pbuf, t);
    hipLaunchKernelGGL(k_red, dim3(NBLK), dim3(NT), 0, stream,
                       cls_b, pbuf, out, amax, t);
  }
}

// Round 9
// 7730.767 us; speedup vs baseline: 2.6256x; 2.6256x over previous
//
#include <hip/hip_runtime.h>
#include <stdint.h>

// Seq2Seq (bi-LSTM encoder + greedy LSTM decoder), MI355X gfx950.
// v9: batch-split classifier (b-split, not K-split), v7 dataflow restored.
//   R8 post-mortem: split-K + k_red regressed 7.6->20.3ms with no counters
//   (rocprof failed; infra degraded). v9 drops everything unique to v8
//   (pbuf, k_red) and instead splits the 32 batches across 2 blocks:
//   grid 512 (pair-swizzled to share XCD L2), cH 16 batches = 74KB ->
//   2 blocks/CU; lane = (kc[0,8) x bg[0,8)) -> w-loads 128B contiguous
//   per instr (2x DRAM efficiency vs v7's 64B), acc = 8 rows x 2 b = 16
//   regs (spill-free), 3-step butterfly + 3-level static row select.
//   k_xg / k_enc / k_cell byte-identical to v7.
//
// B=32 S=128 T=64 V=32000 E=512 H=512 (4H=2048 gates per cell)

#define NT 1024
#define NBLK 256

constexpr int HSTR = 580;    // enc h-stage LDS row stride (512 + pad, %32==4)
constexpr int XSTR = 1156;   // dec [x|h]-stage stride (1024 + pad, %32==4)
constexpr unsigned LDS_ENC = 78336;    // (32*580 + 512 + 512) floats
constexpr unsigned LDS_CELL = 150016;  // (32*1156 + 512) floats
constexpr unsigned LDS_CLS = 74240;    // cH[16][257]f4 + oL[16][130] + amaxL[16]

// workspace layout (bytes)
constexpr size_t OFF_AMAX  = 0;                     // 63*32 u64 = 16128
constexpr size_t OFF_XG    = 17408;                 // 256*128*32*16 f32 = 67108864
constexpr size_t OFF_HENC  = OFF_XG + 67108864ULL;  // 2buf*2dir*32*512 f32 = 262144
constexpr size_t OFF_HCAT  = OFF_HENC + 262144ULL;  // 2buf*32*1024 f32 = 262144
constexpr size_t OFF_CST   = OFF_HCAT + 262144ULL;  // 2dir*32*512 f32 = 131072

__device__ __forceinline__ float sigm(float x) {
  if (x >= 0.f) return 1.f / (1.f + expf(-x));
  float e = expf(x);
  return e / (1.f + e);
}

__device__ __forceinline__ void fma4(const float4& w, const float4& h, float4& a) {
  a.x = fmaf(w.x, h.x, a.x);
  a.y = fmaf(w.y, h.y, a.y);
  a.z = fmaf(w.z, h.z, a.z);
  a.w = fmaf(w.w, h.w, a.w);
}

__device__ __forceinline__ float hsum4(const float4& a) {
  return (a.x + a.y) + (a.z + a.w);
}

__device__ __forceinline__ float dot4(const float4& w, const float4& h, float acc) {
  return fmaf(w.x, h.x, fmaf(w.y, h.y, fmaf(w.z, h.z, fmaf(w.w, h.w, acc))));
}

__device__ __forceinline__ unsigned long long lgkey(float lg, int vr) {
  unsigned u = __float_as_uint(lg);
  u = (u & 0x80000000u) ? ~u : (u | 0x80000000u);
  return ((unsigned long long)u << 32) | (0xFFFFFFFFu - (unsigned)vr);
}

// ---------------- K0: Xg = emb(src) @ wih^T + bih + bhh; init h_enc, out ----
__global__ __launch_bounds__(NT) void k_xg(
    const int* __restrict__ src, const float* __restrict__ enc_emb,
    const float* __restrict__ ewih_f, const float* __restrict__ ebih_f,
    const float* __restrict__ ebhh_f,
    const float* __restrict__ ewih_r, const float* __restrict__ ebih_r,
    const float* __restrict__ ebhh_r,
    float* __restrict__ Xg, float* __restrict__ h_enc, float* __restrict__ out) {
  extern __shared__ float smem[];
  const int tid = threadIdx.x;
  const int bid = blockIdx.x;
  const int d  = bid >> 7;
  const int u0 = (bid & 127) << 2;

  float* hL  = smem;               // [32][HSTR]

  const int rgE = tid >> 7;
  const int bpE = (tid >> 4) & 7;
  const int ksE = tid & 15;
  const int r0E = rgE * 2, r1E = r0E + 1;
  const int growE0 = (r0E & 3) * 512 + u0 + (r0E >> 2);
  const int growE1 = (r1E & 3) * 512 + u0 + (r1E >> 2);

  const float* ewih = d ? ewih_r : ewih_f;
  const float* ebih = d ? ebih_r : ebih_f;
  const float* ebhh = d ? ebhh_r : ebhh_f;

  float4 wA[8], wB[8];
#pragma unroll
  for (int i4 = 0; i4 < 8; ++i4) {
    wA[i4] = *(const float4*)(ewih + (size_t)growE0 * 512 + ksE * 32 + i4 * 4);
    wB[i4] = *(const float4*)(ewih + (size_t)growE1 * 512 + ksE * 32 + i4 * 4);
  }
  const float biasA = ebih[growE0] + ebhh[growE0];
  const float biasB = ebih[growE1] + ebhh[growE1];

  for (int t = 0; t < 128; ++t) {
    {
      int b = tid >> 5, i = tid & 31;
      int tok = src[b * 128 + t];
      const float* row = enc_emb + (size_t)tok * 512;
#pragma unroll
      for (int q = 0; q < 4; ++q) {
        int k = (i + 32 * q) * 4;
        float4 v = *(const float4*)(row + k);
        int pc = k + ((k >> 5) << 2);
        *(float4*)(hL + b * HSTR + pc) = v;
      }
    }
    __syncthreads();
    for (int gi = 0; gi < 4; ++gi) {
      int b = bpE * 4 + gi;
      const float* hb = hL + b * HSTR + ksE * 36;
      float4 a0 = {0, 0, 0, 0}, a1 = {0, 0, 0, 0};
#pragma unroll
      for (int i4 = 0; i4 < 8; ++i4) {
        float4 h4 = *(const float4*)(hb + i4 * 4);
        fma4(wA[i4], h4, a0);
        fma4(wB[i4], h4, a1);
      }
      float s0 = hsum4(a0), s1 = hsum4(a1);
#pragma unroll
      for (int m = 1; m <= 8; m <<= 1) {
        s0 += __shfl_xor(s0, m, 64);
        s1 += __shfl_xor(s1, m, 64);
      }
      if (ksE == 0) {
        float* xgp = Xg + ((size_t)bid << 16) + t * 512 + b * 16;
        xgp[r0E] = s0 + biasA;
        xgp[r1E] = s1 + biasB;
      }
    }
    __syncthreads();
  }

  if (tid < 128) {
    int b = tid & 31, j = tid >> 5;
    h_enc[((0 * 2 + d) * 32 + b) * 512 + u0 + j] = 0.f;
  }
  for (int i = tid; i < 4000; i += NT) {
    int b = i & 31, vv = i >> 5;  // vv < 125
    out[(size_t)b * 64 * 32000 + bid * 125 + vv] = 0.f;
  }
}

// ---------------- K_enc: one bi-LSTM encoder time step ----------------
__global__ __launch_bounds__(NT) void k_enc(
    const float* __restrict__ ewhh_f, const float* __restrict__ ewhh_r,
    const float* __restrict__ Xg, float* __restrict__ h_enc,
    float* __restrict__ hcat, float* __restrict__ c_st, int s) {
  extern __shared__ float smem[];
  const int tid = threadIdx.x;
  const int bid = blockIdx.x;
  const int d  = bid >> 7;
  const int u0 = (bid & 127) << 2;
  const int cur = s & 1;
  const int td = d ? (127 - s) : s;

  float* hL  = smem;               // [32][HSTR]
  float* XgL = smem + 32 * HSTR;   // [32*16]
  float* gL  = XgL + 512;          // [32*16]

  const int rgE = tid >> 7;
  const int bpE = (tid >> 4) & 7;
  const int ksE = tid & 15;
  const int r0E = rgE * 2, r1E = r0E + 1;
  const int growE0 = (r0E & 3) * 512 + u0 + (r0E >> 2);
  const int growE1 = (r1E & 3) * 512 + u0 + (r1E >> 2);

  const float* ewhh = d ? ewhh_r : ewhh_f;

  float4 wA[8], wB[8];
#pragma unroll
  for (int i4 = 0; i4 < 8; ++i4) {
    wA[i4] = *(const float4*)(ewhh + (size_t)growE0 * 512 + ksE * 32 + i4 * 4);
    wB[i4] = *(const float4*)(ewhh + (size_t)growE1 * 512 + ksE * 32 + i4 * 4);
  }

  {
    int b = tid >> 5, i = tid & 31;
    const float* hr = h_enc + ((size_t)(cur * 2 + d) * 32 + b) * 512;
#pragma unroll
    for (int q = 0; q < 4; ++q) {
      int k = (i + 32 * q) * 4;
      float4 v = *(const float4*)(hr + k);
      int pc = k + ((k >> 5) << 2);
      *(float4*)(hL + b * HSTR + pc) = v;
    }
    if (tid < 128) {
      ((float4*)XgL)[tid] =
          *(const float4*)(Xg + ((size_t)bid << 16) + td * 512 + tid * 4);
    }
  }
  __syncthreads();
  for (int gi = 0; gi < 4; ++gi) {
    int b = bpE * 4 + gi;
    const float* hb = hL + b * HSTR + ksE * 36;
    float4 a0 = {0, 0, 0, 0}, a1 = {0, 0, 0, 0};
#pragma unroll
    for (int i4 = 0; i4 < 8; ++i4) {
      float4 h4 = *(const float4*)(hb + i4 * 4);
      fma4(wA[i4], h4, a0);
      fma4(wB[i4], h4, a1);
    }
    float s0 = hsum4(a0), s1 = hsum4(a1);
#pragma unroll
    for (int m = 1; m <= 8; m <<= 1) {
      s0 += __shfl_xor(s0, m, 64);
      s1 += __shfl_xor(s1, m, 64);
    }
    if (ksE == 0) {
      gL[b * 16 + r0E] = s0 + XgL[b * 16 + r0E];
      gL[b * 16 + r1E] = s1 + XgL[b * 16 + r1E];
    }
  }
  __syncthreads();
  if (tid < 128) {
    int b = tid & 31, j = tid >> 5;
    float g_i = gL[b * 16 + (j << 2) + 0];
    float g_f = gL[b * 16 + (j << 2) + 1];
    float g_g = gL[b * 16 + (j << 2) + 2];
    float g_o = gL[b * 16 + (j << 2) + 3];
    float c = (s == 0) ? 0.f : c_st[(d * 32 + b) * 512 + u0 + j];
    c = sigm(g_f) * c + sigm(g_i) * tanhf(g_g);
    float h = sigm(g_o) * tanhf(c);
    c_st[(d * 32 + b) * 512 + u0 + j] = c;
    h_enc[(((cur ^ 1) * 2 + d) * 32 + b) * 512 + u0 + j] = h;
    if (s == 127) hcat[b * 1024 + d * 512 + u0 + j] = h;  // buf 0
  }
}

// ---------------- K_cell: one decoder LSTM step (both dirs) ----------------
__global__ __launch_bounds__(NT) void k_cell(
    const int* __restrict__ tgt, const float* __restrict__ dec_emb,
    const float* __restrict__ dwih_f, const float* __restrict__ dwhh_f,
    const float* __restrict__ dbih_f, const float* __restrict__ dbhh_f,
    const float* __restrict__ dwih_r, const float* __restrict__ dwhh_r,
    const float* __restrict__ dbih_r, const float* __restrict__ dbhh_r,
    float* __restrict__ hcat, float* __restrict__ c_st,
    const unsigned long long* __restrict__ amax, int t) {
  extern __shared__ float smem[];
  const int tid = threadIdx.x;
  const int bid = blockIdx.x;
  const int d  = bid >> 7;
  const int u0 = (bid & 127) << 2;
  const int p = t & 1;

  float* xhL = smem;               // [32][XSTR]
  float* gLd = smem + 32 * XSTR;   // [32*16]

  const int rgD = tid >> 7;
  const int bpD = (tid >> 5) & 3;
  const int ksD = tid & 31;
  const int r0D = rgD * 2, r1D = r0D + 1;
  const int growD0 = (r0D & 3) * 512 + u0 + (r0D >> 2);
  const int growD1 = (r1D & 3) * 512 + u0 + (r1D >> 2);

  const float* dwih = d ? dwih_r : dwih_f;
  const float* dwhh = d ? dwhh_r : dwhh_f;
  const float* dbih = d ? dbih_r : dbih_f;
  const float* dbhh = d ? dbhh_r : dbhh_f;

  {
    int b = tid >> 5, i = tid & 31;
    int tok;
    if (t == 0) {
      tok = tgt[b * 64];
    } else {
      unsigned long long kv = amax[(t - 1) * 32 + b];
      tok = (int)(0xFFFFFFFFu - (unsigned)(kv & 0xFFFFFFFFull));
    }
    const float* xr = dec_emb + (size_t)tok * 512;
    const float* hr = hcat + (size_t)p * 32768 + b * 1024 + d * 512;
#pragma unroll
    for (int q = 0; q < 4; ++q) {
      int k = (i + 32 * q) * 4;
      float4 v = *(const float4*)(xr + k);
      int pc = k + ((k >> 5) << 2);
      *(float4*)(xhL + b * XSTR + pc) = v;
    }
#pragma unroll
    for (int q = 0; q < 4; ++q) {
      int k = (i + 32 * q) * 4;
      float4 v = *(const float4*)(hr + k);
      int c2 = 512 + k;
      int pc = c2 + ((c2 >> 5) << 2);
      *(float4*)(xhL + b * XSTR + pc) = v;
    }
  }
  float4 wA[8], wB[8];
  {
    const float* s0p = (ksD < 16) ? (dwih + (size_t)growD0 * 512 + ksD * 32)
                                  : (dwhh + (size_t)growD0 * 512 + (ksD - 16) * 32);
    const float* s1p = (ksD < 16) ? (dwih + (size_t)growD1 * 512 + ksD * 32)
                                  : (dwhh + (size_t)growD1 * 512 + (ksD - 16) * 32);
#pragma unroll
    for (int i4 = 0; i4 < 8; ++i4) {
      wA[i4] = *(const float4*)(s0p + i4 * 4);
      wB[i4] = *(const float4*)(s1p + i4 * 4);
    }
  }
  const float biasA = dbih[growD0] + dbhh[growD0];
  const float biasB = dbih[growD1] + dbhh[growD1];
  __syncthreads();
  for (int gi = 0; gi < 8; ++gi) {
    int b = bpD * 8 + gi;
    const float* hb = xhL + b * XSTR + ksD * 36;
    float4 a0 = {0, 0, 0, 0}, a1 = {0, 0, 0, 0};
#pragma unroll
    for (int i4 = 0; i4 < 8; ++i4) {
      float4 h4 = *(const float4*)(hb + i4 * 4);
      fma4(wA[i4], h4, a0);
      fma4(wB[i4], h4, a1);
    }
    float s0 = hsum4(a0), s1 = hsum4(a1);
#pragma unroll
    for (int m = 1; m <= 16; m <<= 1) {
      s0 += __shfl_xor(s0, m, 64);
      s1 += __shfl_xor(s1, m, 64);
    }
    if (ksD == 0) {
      gLd[b * 16 + r0D] = s0 + biasA;
      gLd[b * 16 + r1D] = s1 + biasB;
    }
  }
  __syncthreads();
  if (tid < 128) {
    int b = tid & 31, j = tid >> 5;
    float g_i = gLd[b * 16 + (j << 2) + 0];
    float g_f = gLd[b * 16 + (j << 2) + 1];
    float g_g = gLd[b * 16 + (j << 2) + 2];
    float g_o = gLd[b * 16 + (j << 2) + 3];
    float c = c_st[(d * 32 + b) * 512 + u0 + j];
    c = sigm(g_f) * c + sigm(g_i) * tanhf(g_g);
    float h = sigm(g_o) * tanhf(c);
    c_st[(d * 32 + b) * 512 + u0 + j] = c;
    hcat[(size_t)(p ^ 1) * 32768 + b * 1024 + d * 512 + u0 + j] = h;
  }
}

// ---------------- K_cls v9: batch-split classifier ----------------
// grid 512: n -> g = (n>>4)*8 + (n&7), bh = (n>>3)&1  (pairs share an XCD).
// Block handles 125 rows x 16 batches (b = bh*16 + lb). cH 16 batches ->
// 74 KB -> 2 blocks/CU. lane = (bg[0,8) x kc[0,8)): w-loads 128B contiguous
// per instr; acc = 8 rows x 2 b = 16 regs; butterfly(1,2,4) + 3-level select.
__global__ __launch_bounds__(NT, 4) void k_cls(
    const float* __restrict__ cls_w, const float* __restrict__ cls_b,
    const float* __restrict__ hcat, unsigned long long* __restrict__ amax,
    float* __restrict__ out, int t) {
  extern __shared__ float smem[];
  const int tid = threadIdx.x;
  const int n = blockIdx.x;
  const int g  = (n >> 4) * 8 + (n & 7);
  const int bh = (n >> 3) & 1;
  const int p = t & 1;

  // LDS: cH float4[16][257] floats [0,16448); oL floats [16448,18528);
  //      amaxL u64[16] at float 18528 (byte 74112)
  float* oL = smem + 16448;
  unsigned long long* amaxL = (unsigned long long*)(smem + 18528);

  {  // stage this batch-half of h; zero amaxL
    const float4* hr4 = (const float4*)(hcat + (size_t)(p ^ 1) * 32768);
    float4* cH4w = (float4*)smem;
#pragma unroll
    for (int q = 0; q < 4; ++q) {
      int f = tid + q * 1024;        // [0,4096)
      int lb = f >> 8, k4 = f & 255;
      cH4w[lb * 257 + k4] = hr4[(bh * 16 + lb) * 256 + k4];
    }
    if (tid < 16) amaxL[tid] = 0ull;
  }
  __syncthreads();
  {
    const int lane = tid & 63;
    const int widu = __builtin_amdgcn_readfirstlane(tid >> 6);
    const int kc = lane & 7;          // k-chunk [0,8); also the kept row
    const int bg = lane >> 3;         // batch-pair [0,8)
    const int lb0 = bg * 2, lb1 = lb0 + 1;
    const float4* cH4 = (const float4*)smem;

    const float* wr[8];
#pragma unroll
    for (int r = 0; r < 8; ++r) {
      int lr = widu * 8 + r;
      lr = lr > 124 ? 124 : lr;      // rows 125..127 clamped (stores guarded)
      wr[r] = cls_w + (size_t)(g * 125 + lr) * 1024;
    }

    float acc[16];
#pragma unroll
    for (int i = 0; i < 16; ++i) acc[i] = 0.f;

    const float4* hp0 = cH4 + lb0 * 257 + kc;
    const float4* hp1 = cH4 + lb1 * 257 + kc;
#pragma unroll 2
    for (int q = 0; q < 32; ++q) {
      const int ko = q * 32 + kc * 4;   // 8 kc lanes cover 128B contiguous
      float4 w0 = *(const float4*)(wr[0] + ko);
      float4 w1 = *(const float4*)(wr[1] + ko);
      float4 w2 = *(const float4*)(wr[2] + ko);
      float4 w3 = *(const float4*)(wr[3] + ko);
      float4 w4 = *(const float4*)(wr[4] + ko);
      float4 w5 = *(const float4*)(wr[5] + ko);
      float4 w6 = *(const float4*)(wr[6] + ko);
      float4 w7 = *(const float4*)(wr[7] + ko);
      float4 h40 = hp0[q * 8];
      float4 h41 = hp1[q * 8];
      acc[0]  = dot4(w0, h40, acc[0]);   acc[1]  = dot4(w0, h41, acc[1]);
      acc[2]  = dot4(w1, h40, acc[2]);   acc[3]  = dot4(w1, h41, acc[3]);
      acc[4]  = dot4(w2, h40, acc[4]);   acc[5]  = dot4(w2, h41, acc[5]);
      acc[6]  = dot4(w3, h40, acc[6]);   acc[7]  = dot4(w3, h41, acc[7]);
      acc[8]  = dot4(w4, h40, acc[8]);   acc[9]  = dot4(w4, h41, acc[9]);
      acc[10] = dot4(w5, h40, acc[10]);  acc[11] = dot4(w5, h41, acc[11]);
      acc[12] = dot4(w6, h40, acc[12]);  acc[13] = dot4(w6, h41, acc[13]);
      acc[14] = dot4(w7, h40, acc[14]);  acc[15] = dot4(w7, h41, acc[15]);
    }

    // butterfly-sum over the 8 kc lanes (masks 1,2,4)
#pragma unroll
    for (int i = 0; i < 16; ++i) {
      acc[i] += __shfl_xor(acc[i], 1, 64);
      acc[i] += __shfl_xor(acc[i], 2, 64);
      acc[i] += __shfl_xor(acc[i], 4, 64);
    }

    // static 3-level row select: lane kc keeps row r=kc (acc idx r*2+j)
    float s0v, s1v;
    {
      float a0 = (kc & 4) ? acc[8]  : acc[0];
      float a1 = (kc & 4) ? acc[10] : acc[2];
      float a2 = (kc & 4) ? acc[12] : acc[4];
      float a3 = (kc & 4) ? acc[14] : acc[6];
      float t0 = (kc & 2) ? a2 : a0;
      float t1 = (kc & 2) ? a3 : a1;
      s0v = (kc & 1) ? t1 : t0;
      float b0 = (kc & 4) ? acc[9]  : acc[1];
      float b1 = (kc & 4) ? acc[11] : acc[3];
      float b2 = (kc & 4) ? acc[13] : acc[5];
      float b3 = (kc & 4) ? acc[15] : acc[7];
      float u0 = (kc & 2) ? b2 : b0;
      float u1 = (kc & 2) ? b3 : b1;
      s1v = (kc & 1) ? u1 : u0;
    }

    const int lrA = widu * 8 + kc;       // up to 127; >=125 invalid
    const int lrAc = lrA > 124 ? 124 : lrA;
    const int vr = g * 125 + lrAc;
    const float cb = cls_b[vr];
    const float lg0 = s0v + cb;          // (row lrA, local batch lb0)
    const float lg1 = s1v + cb;          // (row lrA, local batch lb1)

    unsigned long long k0 = 0ull, k1 = 0ull;
    if (lrA < 125) {
      oL[lb0 * 130 + lrA] = lg0;
      oL[lb1 * 130 + lrA] = lg1;
      k0 = lgkey(lg0, vr);
      k1 = lgkey(lg1, vr);
    }
    // max over the 8 kc lanes (rows of this wave) for each batch
#pragma unroll
    for (int m = 1; m <= 4; m <<= 1) {
      unsigned long long o0 = __shfl_xor(k0, m, 64);
      unsigned long long o1 = __shfl_xor(k1, m, 64);
      k0 = o0 > k0 ? o0 : k0;
      k1 = o1 > k1 ? o1 : k1;
    }
    if (kc == 0) {
      atomicMax(&amaxL[lb0], k0);
      atomicMax(&amaxL[lb1], k1);
    }
  }
  __syncthreads();
  // coalesced logit writeback + global argmax merge
#pragma unroll
  for (int it = 0; it < 2; ++it) {
    int idx = tid + it * 1024;            // [0,2048)
    int lb = idx >> 7, j = idx & 127;
    if (j < 125)
      out[((size_t)(bh * 16 + lb) * 64 + (t + 1)) * 32000 + g * 125 + j] =
          oL[lb * 130 + j];
  }
  if (tid < 16) atomicMax(&amax[t * 32 + bh * 16 + tid], amaxL[tid]);
}

extern "C" void kernel_launch(void* const* d_in, const int* in_sizes, int n_in,
                              void* d_out, int out_size, void* d_ws, size_t ws_size,
                              hipStream_t stream) {
  (void)in_sizes; (void)n_in; (void)out_size; (void)ws_size;
  const int*   src     = (const int*)d_in[0];
  const int*   tgt     = (const int*)d_in[1];
  const float* enc_emb = (const float*)d_in[2];
  const float* dec_emb = (const float*)d_in[3];
  const float* ewih_f  = (const float*)d_in[4];
  const float* ewhh_f  = (const float*)d_in[5];
  const float* ebih_f  = (const float*)d_in[6];
  const float* ebhh_f  = (const float*)d_in[7];
  const float* ewih_r  = (const float*)d_in[8];
  const float* ewhh_r  = (const float*)d_in[9];
  const float* ebih_r  = (const float*)d_in[10];
  const float* ebhh_r  = (const float*)d_in[11];
  const float* dwih_f  = (const float*)d_in[12];
  const float* dwhh_f  = (const float*)d_in[13];
  const float* dbih_f  = (const float*)d_in[14];
  const float* dbhh_f  = (const float*)d_in[15];
  const float* dwih_r  = (const float*)d_in[16];
  const float* dwhh_r  = (const float*)d_in[17];
  const float* dbih_r  = (const float*)d_in[18];
  const float* dbhh_r  = (const float*)d_in[19];
  const float* cls_w   = (const float*)d_in[20];
  const float* cls_b   = (const float*)d_in[21];

  char* ws = (char*)d_ws;
  unsigned long long* amax = (unsigned long long*)(ws + OFF_AMAX);
  float* Xg                = (float*)(ws + OFF_XG);
  float* h_enc             = (float*)(ws + OFF_HENC);
  float* hcat              = (float*)(ws + OFF_HCAT);
  float* c_st              = (float*)(ws + OFF_CST);
  float* out               = (float*)d_out;

  // reset argmax slots (monotone atomicMax needs zeros each call)
  hipMemsetAsync(d_ws, 0, OFF_XG, stream);

  hipFuncSetAttribute((const void*)k_xg,
                      hipFuncAttributeMaxDynamicSharedMemorySize, LDS_ENC);
  hipFuncSetAttribute((const void*)k_enc,
                      hipFuncAttributeMaxDynamicSharedMemorySize, LDS_ENC);
  hipFuncSetAttribute((const void*)k_cell,
                      hipFuncAttributeMaxDynamicSharedMemorySize, LDS_CELL);
  hipFuncSetAttribute((const void*)k_cls,
                      hipFuncAttributeMaxDynamicSharedMemorySize, LDS_CLS);

  hipLaunchKernelGGL(k_xg, dim3(NBLK), dim3(NT), LDS_ENC, stream,
                     src, enc_emb, ewih_f, ebih_f, ebhh_f,
                     ewih_r, ebih_r, ebhh_r, Xg, h_enc, out);

  for (int s = 0; s < 128; ++s) {
    hipLaunchKernelGGL(k_enc, dim3(NBLK), dim3(NT), LDS_ENC, stream,
                       ewhh_f, ewhh_r, Xg, h_enc, hcat, c_st, s);
  }

  for (int t = 0; t < 63; ++t) {
    hipLaunchKernelGGL(k_cell, dim3(NBLK), dim3(NT), LDS_CELL, stream,
                       tgt, dec_emb,
                       dwih_f, dwhh_f, dbih_f, dbhh_f,
                       dwih_r, dwhh_r, dbih_r, dbhh_r,
                       hcat, c_st, amax, t);
    hipLaunchKernelGGL(k_cls, dim3(NBLK * 2), dim3(NT), LDS_CLS, stream,
                       cls_w, cls_b, hcat, amax, out, t);
  }
}

// Round 10
// 7662.411 us; speedup vs baseline: 2.6490x; 1.0089x over previous
//
#include <hip/hip_runtime.h>
#include <stdint.h>

// Seq2Seq (bi-LSTM encoder + greedy LSTM decoder), MI355X gfx950.
// v10: v9 + non-temporal stores for `out`.
//   R9 post-mortem: v9 (b-split, 2 blk/CU, 128B-coalesced w-loads) == v7 ->
//   k_cls is not issue/LDS/occupancy-bound. R6 counters re-read: FETCH =
//   63 x 131MB = cls_w re-fetched from HBM EVERY step; L3 does not retain
//   it (logit write-allocate churn). Fix: `out` is write-once-never-read ->
//   __builtin_nontemporal_store keeps the 258MB logit stream out of L3,
//   letting cls_w stay resident. Everything else byte-identical to v9.
//   Signature: FETCH 8.4e6 -> <=1.5e6 KB if retention wins.
//
// B=32 S=128 T=64 V=32000 E=512 H=512 (4H=2048 gates per cell)

#define NT 1024
#define NBLK 256

constexpr int HSTR = 580;    // enc h-stage LDS row stride (512 + pad, %32==4)
constexpr int XSTR = 1156;   // dec [x|h]-stage stride (1024 + pad, %32==4)
constexpr unsigned LDS_ENC = 78336;    // (32*580 + 512 + 512) floats
constexpr unsigned LDS_CELL = 150016;  // (32*1156 + 512) floats
constexpr unsigned LDS_CLS = 74240;    // cH[16][257]f4 + oL[16][130] + amaxL[16]

// workspace layout (bytes)
constexpr size_t OFF_AMAX  = 0;                     // 63*32 u64 = 16128
constexpr size_t OFF_XG    = 17408;                 // 256*128*32*16 f32 = 67108864
constexpr size_t OFF_HENC  = OFF_XG + 67108864ULL;  // 2buf*2dir*32*512 f32 = 262144
constexpr size_t OFF_HCAT  = OFF_HENC + 262144ULL;  // 2buf*32*1024 f32 = 262144
constexpr size_t OFF_CST   = OFF_HCAT + 262144ULL;  // 2dir*32*512 f32 = 131072

__device__ __forceinline__ float sigm(float x) {
  if (x >= 0.f) return 1.f / (1.f + expf(-x));
  float e = expf(x);
  return e / (1.f + e);
}

__device__ __forceinline__ void fma4(const float4& w, const float4& h, float4& a) {
  a.x = fmaf(w.x, h.x, a.x);
  a.y = fmaf(w.y, h.y, a.y);
  a.z = fmaf(w.z, h.z, a.z);
  a.w = fmaf(w.w, h.w, a.w);
}

__device__ __forceinline__ float hsum4(const float4& a) {
  return (a.x + a.y) + (a.z + a.w);
}

__device__ __forceinline__ float dot4(const float4& w, const float4& h, float acc) {
  return fmaf(w.x, h.x, fmaf(w.y, h.y, fmaf(w.z, h.z, fmaf(w.w, h.w, acc))));
}

__device__ __forceinline__ unsigned long long lgkey(float lg, int vr) {
  unsigned u = __float_as_uint(lg);
  u = (u & 0x80000000u) ? ~u : (u | 0x80000000u);
  return ((unsigned long long)u << 32) | (0xFFFFFFFFu - (unsigned)vr);
}

// ---------------- K0: Xg = emb(src) @ wih^T + bih + bhh; init h_enc, out ----
__global__ __launch_bounds__(NT) void k_xg(
    const int* __restrict__ src, const float* __restrict__ enc_emb,
    const float* __restrict__ ewih_f, const float* __restrict__ ebih_f,
    const float* __restrict__ ebhh_f,
    const float* __restrict__ ewih_r, const float* __restrict__ ebih_r,
    const float* __restrict__ ebhh_r,
    float* __restrict__ Xg, float* __restrict__ h_enc, float* __restrict__ out) {
  extern __shared__ float smem[];
  const int tid = threadIdx.x;
  const int bid = blockIdx.x;
  const int d  = bid >> 7;
  const int u0 = (bid & 127) << 2;

  float* hL  = smem;               // [32][HSTR]

  const int rgE = tid >> 7;
  const int bpE = (tid >> 4) & 7;
  const int ksE = tid & 15;
  const int r0E = rgE * 2, r1E = r0E + 1;
  const int growE0 = (r0E & 3) * 512 + u0 + (r0E >> 2);
  const int growE1 = (r1E & 3) * 512 + u0 + (r1E >> 2);

  const float* ewih = d ? ewih_r : ewih_f;
  const float* ebih = d ? ebih_r : ebih_f;
  const float* ebhh = d ? ebhh_r : ebhh_f;

  float4 wA[8], wB[8];
#pragma unroll
  for (int i4 = 0; i4 < 8; ++i4) {
    wA[i4] = *(const float4*)(ewih + (size_t)growE0 * 512 + ksE * 32 + i4 * 4);
    wB[i4] = *(const float4*)(ewih + (size_t)growE1 * 512 + ksE * 32 + i4 * 4);
  }
  const float biasA = ebih[growE0] + ebhh[growE0];
  const float biasB = ebih[growE1] + ebhh[growE1];

  for (int t = 0; t < 128; ++t) {
    {
      int b = tid >> 5, i = tid & 31;
      int tok = src[b * 128 + t];
      const float* row = enc_emb + (size_t)tok * 512;
#pragma unroll
      for (int q = 0; q < 4; ++q) {
        int k = (i + 32 * q) * 4;
        float4 v = *(const float4*)(row + k);
        int pc = k + ((k >> 5) << 2);
        *(float4*)(hL + b * HSTR + pc) = v;
      }
    }
    __syncthreads();
    for (int gi = 0; gi < 4; ++gi) {
      int b = bpE * 4 + gi;
      const float* hb = hL + b * HSTR + ksE * 36;
      float4 a0 = {0, 0, 0, 0}, a1 = {0, 0, 0, 0};
#pragma unroll
      for (int i4 = 0; i4 < 8; ++i4) {
        float4 h4 = *(const float4*)(hb + i4 * 4);
        fma4(wA[i4], h4, a0);
        fma4(wB[i4], h4, a1);
      }
      float s0 = hsum4(a0), s1 = hsum4(a1);
#pragma unroll
      for (int m = 1; m <= 8; m <<= 1) {
        s0 += __shfl_xor(s0, m, 64);
        s1 += __shfl_xor(s1, m, 64);
      }
      if (ksE == 0) {
        float* xgp = Xg + ((size_t)bid << 16) + t * 512 + b * 16;
        xgp[r0E] = s0 + biasA;
        xgp[r1E] = s1 + biasB;
      }
    }
    __syncthreads();
  }

  if (tid < 128) {
    int b = tid & 31, j = tid >> 5;
    h_enc[((0 * 2 + d) * 32 + b) * 512 + u0 + j] = 0.f;
  }
  for (int i = tid; i < 4000; i += NT) {
    int b = i & 31, vv = i >> 5;  // vv < 125
    __builtin_nontemporal_store(0.f,
        &out[(size_t)b * 64 * 32000 + bid * 125 + vv]);
  }
}

// ---------------- K_enc: one bi-LSTM encoder time step ----------------
__global__ __launch_bounds__(NT) void k_enc(
    const float* __restrict__ ewhh_f, const float* __restrict__ ewhh_r,
    const float* __restrict__ Xg, float* __restrict__ h_enc,
    float* __restrict__ hcat, float* __restrict__ c_st, int s) {
  extern __shared__ float smem[];
  const int tid = threadIdx.x;
  const int bid = blockIdx.x;
  const int d  = bid >> 7;
  const int u0 = (bid & 127) << 2;
  const int cur = s & 1;
  const int td = d ? (127 - s) : s;

  float* hL  = smem;               // [32][HSTR]
  float* XgL = smem + 32 * HSTR;   // [32*16]
  float* gL  = XgL + 512;          // [32*16]

  const int rgE = tid >> 7;
  const int bpE = (tid >> 4) & 7;
  const int ksE = tid & 15;
  const int r0E = rgE * 2, r1E = r0E + 1;
  const int growE0 = (r0E & 3) * 512 + u0 + (r0E >> 2);
  const int growE1 = (r1E & 3) * 512 + u0 + (r1E >> 2);

  const float* ewhh = d ? ewhh_r : ewhh_f;

  float4 wA[8], wB[8];
#pragma unroll
  for (int i4 = 0; i4 < 8; ++i4) {
    wA[i4] = *(const float4*)(ewhh + (size_t)growE0 * 512 + ksE * 32 + i4 * 4);
    wB[i4] = *(const float4*)(ewhh + (size_t)growE1 * 512 + ksE * 32 + i4 * 4);
  }

  {
    int b = tid >> 5, i = tid & 31;
    const float* hr = h_enc + ((size_t)(cur * 2 + d) * 32 + b) * 512;
#pragma unroll
    for (int q = 0; q < 4; ++q) {
      int k = (i + 32 * q) * 4;
      float4 v = *(const float4*)(hr + k);
      int pc = k + ((k >> 5) << 2);
      *(float4*)(hL + b * HSTR + pc) = v;
    }
    if (tid < 128) {
      ((float4*)XgL)[tid] =
          *(const float4*)(Xg + ((size_t)bid << 16) + td * 512 + tid * 4);
    }
  }
  __syncthreads();
  for (int gi = 0; gi < 4; ++gi) {
    int b = bpE * 4 + gi;
    const float* hb = hL + b * HSTR + ksE * 36;
    float4 a0 = {0, 0, 0, 0}, a1 = {0, 0, 0, 0};
#pragma unroll
    for (int i4 = 0; i4 < 8; ++i4) {
      float4 h4 = *(const float4*)(hb + i4 * 4);
      fma4(wA[i4], h4, a0);
      fma4(wB[i4], h4, a1);
    }
    float s0 = hsum4(a0), s1 = hsum4(a1);
#pragma unroll
    for (int m = 1; m <= 8; m <<= 1) {
      s0 += __shfl_xor(s0, m, 64);
      s1 += __shfl_xor(s1, m, 64);
    }
    if (ksE == 0) {
      gL[b * 16 + r0E] = s0 + XgL[b * 16 + r0E];
      gL[b * 16 + r1E] = s1 + XgL[b * 16 + r1E];
    }
  }
  __syncthreads();
  if (tid < 128) {
    int b = tid & 31, j = tid >> 5;
    float g_i = gL[b * 16 + (j << 2) + 0];
    float g_f = gL[b * 16 + (j << 2) + 1];
    float g_g = gL[b * 16 + (j << 2) + 2];
    float g_o = gL[b * 16 + (j << 2) + 3];
    float c = (s == 0) ? 0.f : c_st[(d * 32 + b) * 512 + u0 + j];
    c = sigm(g_f) * c + sigm(g_i) * tanhf(g_g);
    float h = sigm(g_o) * tanhf(c);
    c_st[(d * 32 + b) * 512 + u0 + j] = c;
    h_enc[(((cur ^ 1) * 2 + d) * 32 + b) * 512 + u0 + j] = h;
    if (s == 127) hcat[b * 1024 + d * 512 + u0 + j] = h;  // buf 0
  }
}

// ---------------- K_cell: one decoder LSTM step (both dirs) ----------------
__global__ __launch_bounds__(NT) void k_cell(
    const int* __restrict__ tgt, const float* __restrict__ dec_emb,
    const float* __restrict__ dwih_f, const float* __restrict__ dwhh_f,
    const float* __restrict__ dbih_f, const float* __restrict__ dbhh_f,
    const float* __restrict__ dwih_r, const float* __restrict__ dwhh_r,
    const float* __restrict__ dbih_r, const float* __restrict__ dbhh_r,
    float* __restrict__ hcat, float* __restrict__ c_st,
    const unsigned long long* __restrict__ amax, int t) {
  extern __shared__ float smem[];
  const int tid = threadIdx.x;
  const int bid = blockIdx.x;
  const int d  = bid >> 7;
  const int u0 = (bid & 127) << 2;
  const int p = t & 1;

  float* xhL = smem;               // [32][XSTR]
  float* gLd = smem + 32 * XSTR;   // [32*16]

  const int rgD = tid >> 7;
  const int bpD = (tid >> 5) & 3;
  const int ksD = tid & 31;
  const int r0D = rgD * 2, r1D = r0D + 1;
  const int growD0 = (r0D & 3) * 512 + u0 + (r0D >> 2);
  const int growD1 = (r1D & 3) * 512 + u0 + (r1D >> 2);

  const float* dwih = d ? dwih_r : dwih_f;
  const float* dwhh = d ? dwhh_r : dwhh_f;
  const float* dbih = d ? dbih_r : dbih_f;
  const float* dbhh = d ? dbhh_r : dbhh_f;

  {
    int b = tid >> 5, i = tid & 31;
    int tok;
    if (t == 0) {
      tok = tgt[b * 64];
    } else {
      unsigned long long kv = amax[(t - 1) * 32 + b];
      tok = (int)(0xFFFFFFFFu - (unsigned)(kv & 0xFFFFFFFFull));
    }
    const float* xr = dec_emb + (size_t)tok * 512;
    const float* hr = hcat + (size_t)p * 32768 + b * 1024 + d * 512;
#pragma unroll
    for (int q = 0; q < 4; ++q) {
      int k = (i + 32 * q) * 4;
      float4 v = *(const float4*)(xr + k);
      int pc = k + ((k >> 5) << 2);
      *(float4*)(xhL + b * XSTR + pc) = v;
    }
#pragma unroll
    for (int q = 0; q < 4; ++q) {
      int k = (i + 32 * q) * 4;
      float4 v = *(const float4*)(hr + k);
      int c2 = 512 + k;
      int pc = c2 + ((c2 >> 5) << 2);
      *(float4*)(xhL + b * XSTR + pc) = v;
    }
  }
  float4 wA[8], wB[8];
  {
    const float* s0p = (ksD < 16) ? (dwih + (size_t)growD0 * 512 + ksD * 32)
                                  : (dwhh + (size_t)growD0 * 512 + (ksD - 16) * 32);
    const float* s1p = (ksD < 16) ? (dwih + (size_t)growD1 * 512 + ksD * 32)
                                  : (dwhh + (size_t)growD1 * 512 + (ksD - 16) * 32);
#pragma unroll
    for (int i4 = 0; i4 < 8; ++i4) {
      wA[i4] = *(const float4*)(s0p + i4 * 4);
      wB[i4] = *(const float4*)(s1p + i4 * 4);
    }
  }
  const float biasA = dbih[growD0] + dbhh[growD0];
  const float biasB = dbih[growD1] + dbhh[growD1];
  __syncthreads();
  for (int gi = 0; gi < 8; ++gi) {
    int b = bpD * 8 + gi;
    const float* hb = xhL + b * XSTR + ksD * 36;
    float4 a0 = {0, 0, 0, 0}, a1 = {0, 0, 0, 0};
#pragma unroll
    for (int i4 = 0; i4 < 8; ++i4) {
      float4 h4 = *(const float4*)(hb + i4 * 4);
      fma4(wA[i4], h4, a0);
      fma4(wB[i4], h4, a1);
    }
    float s0 = hsum4(a0), s1 = hsum4(a1);
#pragma unroll
    for (int m = 1; m <= 16; m <<= 1) {
      s0 += __shfl_xor(s0, m, 64);
      s1 += __shfl_xor(s1, m, 64);
    }
    if (ksD == 0) {
      gLd[b * 16 + r0D] = s0 + biasA;
      gLd[b * 16 + r1D] = s1 + biasB;
    }
  }
  __syncthreads();
  if (tid < 128) {
    int b = tid & 31, j = tid >> 5;
    float g_i = gLd[b * 16 + (j << 2) + 0];
    float g_f = gLd[b * 16 + (j << 2) + 1];
    float g_g = gLd[b * 16 + (j << 2) + 2];
    float g_o = gLd[b * 16 + (j << 2) + 3];
    float c = c_st[(d * 32 + b) * 512 + u0 + j];
    c = sigm(g_f) * c + sigm(g_i) * tanhf(g_g);
    float h = sigm(g_o) * tanhf(c);
    c_st[(d * 32 + b) * 512 + u0 + j] = c;
    hcat[(size_t)(p ^ 1) * 32768 + b * 1024 + d * 512 + u0 + j] = h;
  }
}

// ---------------- K_cls v10: batch-split classifier, NT out stores --------
// grid 512: n -> g = (n>>4)*8 + (n&7), bh = (n>>3)&1  (pairs share an XCD).
// Block handles 125 rows x 16 batches (b = bh*16 + lb). cH 16 batches ->
// 74 KB -> 2 blocks/CU. lane = (bg[0,8) x kc[0,8)): w-loads 128B contiguous
// per instr; acc = 8 rows x 2 b = 16 regs; butterfly(1,2,4) + 3-level select.
__global__ __launch_bounds__(NT, 4) void k_cls(
    const float* __restrict__ cls_w, const float* __restrict__ cls_b,
    const float* __restrict__ hcat, unsigned long long* __restrict__ amax,
    float* __restrict__ out, int t) {
  extern __shared__ float smem[];
  const int tid = threadIdx.x;
  const int n = blockIdx.x;
  const int g  = (n >> 4) * 8 + (n & 7);
  const int bh = (n >> 3) & 1;
  const int p = t & 1;

  // LDS: cH float4[16][257] floats [0,16448); oL floats [16448,18528);
  //      amaxL u64[16] at float 18528 (byte 74112)
  float* oL = smem + 16448;
  unsigned long long* amaxL = (unsigned long long*)(smem + 18528);

  {  // stage this batch-half of h; zero amaxL
    const float4* hr4 = (const float4*)(hcat + (size_t)(p ^ 1) * 32768);
    float4* cH4w = (float4*)smem;
#pragma unroll
    for (int q = 0; q < 4; ++q) {
      int f = tid + q * 1024;        // [0,4096)
      int lb = f >> 8, k4 = f & 255;
      cH4w[lb * 257 + k4] = hr4[(bh * 16 + lb) * 256 + k4];
    }
    if (tid < 16) amaxL[tid] = 0ull;
  }
  __syncthreads();
  {
    const int lane = tid & 63;
    const int widu = __builtin_amdgcn_readfirstlane(tid >> 6);
    const int kc = lane & 7;          // k-chunk [0,8); also the kept row
    const int bg = lane >> 3;         // batch-pair [0,8)
    const int lb0 = bg * 2, lb1 = lb0 + 1;
    const float4* cH4 = (const float4*)smem;

    const float* wr[8];
#pragma unroll
    for (int r = 0; r < 8; ++r) {
      int lr = widu * 8 + r;
      lr = lr > 124 ? 124 : lr;      // rows 125..127 clamped (stores guarded)
      wr[r] = cls_w + (size_t)(g * 125 + lr) * 1024;
    }

    float acc[16];
#pragma unroll
    for (int i = 0; i < 16; ++i) acc[i] = 0.f;

    const float4* hp0 = cH4 + lb0 * 257 + kc;
    const float4* hp1 = cH4 + lb1 * 257 + kc;
#pragma unroll 2
    for (int q = 0; q < 32; ++q) {
      const int ko = q * 32 + kc * 4;   // 8 kc lanes cover 128B contiguous
      float4 w0 = *(const float4*)(wr[0] + ko);
      float4 w1 = *(const float4*)(wr[1] + ko);
      float4 w2 = *(const float4*)(wr[2] + ko);
      float4 w3 = *(const float4*)(wr[3] + ko);
      float4 w4 = *(const float4*)(wr[4] + ko);
      float4 w5 = *(const float4*)(wr[5] + ko);
      float4 w6 = *(const float4*)(wr[6] + ko);
      float4 w7 = *(const float4*)(wr[7] + ko);
      float4 h40 = hp0[q * 8];
      float4 h41 = hp1[q * 8];
      acc[0]  = dot4(w0, h40, acc[0]);   acc[1]  = dot4(w0, h41, acc[1]);
      acc[2]  = dot4(w1, h40, acc[2]);   acc[3]  = dot4(w1, h41, acc[3]);
      acc[4]  = dot4(w2, h40, acc[4]);   acc[5]  = dot4(w2, h41, acc[5]);
      acc[6]  = dot4(w3, h40, acc[6]);   acc[7]  = dot4(w3, h41, acc[7]);
      acc[8]  = dot4(w4, h40, acc[8]);   acc[9]  = dot4(w4, h41, acc[9]);
      acc[10] = dot4(w5, h40, acc[10]);  acc[11] = dot4(w5, h41, acc[11]);
      acc[12] = dot4(w6, h40, acc[12]);  acc[13] = dot4(w6, h41, acc[13]);
      acc[14] = dot4(w7, h40, acc[14]);  acc[15] = dot4(w7, h41, acc[15]);
    }

    // butterfly-sum over the 8 kc lanes (masks 1,2,4)
#pragma unroll
    for (int i = 0; i < 16; ++i) {
      acc[i] += __shfl_xor(acc[i], 1, 64);
      acc[i] += __shfl_xor(acc[i], 2, 64);
      acc[i] += __shfl_xor(acc[i], 4, 64);
    }

    // static 3-level row select: lane kc keeps row r=kc (acc idx r*2+j)
    float s0v, s1v;
    {
      float a0 = (kc & 4) ? acc[8]  : acc[0];
      float a1 = (kc & 4) ? acc[10] : acc[2];
      float a2 = (kc & 4) ? acc[12] : acc[4];
      float a3 = (kc & 4) ? acc[14] : acc[6];
      float t0 = (kc & 2) ? a2 : a0;
      float t1 = (kc & 2) ? a3 : a1;
      s0v = (kc & 1) ? t1 : t0;
      float b0 = (kc & 4) ? acc[9]  : acc[1];
      float b1 = (kc & 4) ? acc[11] : acc[3];
      float b2 = (kc & 4) ? acc[13] : acc[5];
      float b3 = (kc & 4) ? acc[15] : acc[7];
      float u0 = (kc & 2) ? b2 : b0;
      float u1 = (kc & 2) ? b3 : b1;
      s1v = (kc & 1) ? u1 : u0;
    }

    const int lrA = widu * 8 + kc;       // up to 127; >=125 invalid
    const int lrAc = lrA > 124 ? 124 : lrA;
    const int vr = g * 125 + lrAc;
    const float cb = cls_b[vr];
    const float lg0 = s0v + cb;          // (row lrA, local batch lb0)
    const float lg1 = s1v + cb;          // (row lrA, local batch lb1)

    unsigned long long k0 = 0ull, k1 = 0ull;
    if (lrA < 125) {
      oL[lb0 * 130 + lrA] = lg0;
      oL[lb1 * 130 + lrA] = lg1;
      k0 = lgkey(lg0, vr);
      k1 = lgkey(lg1, vr);
    }
    // max over the 8 kc lanes (rows of this wave) for each batch
#pragma unroll
    for (int m = 1; m <= 4; m <<= 1) {
      unsigned long long o0 = __shfl_xor(k0, m, 64);
      unsigned long long o1 = __shfl_xor(k1, m, 64);
      k0 = o0 > k0 ? o0 : k0;
      k1 = o1 > k1 ? o1 : k1;
    }
    if (kc == 0) {
      atomicMax(&amaxL[lb0], k0);
      atomicMax(&amaxL[lb1], k1);
    }
  }
  __syncthreads();
  // coalesced logit writeback (non-temporal: out is never re-read on GPU)
#pragma unroll
  for (int it = 0; it < 2; ++it) {
    int idx = tid + it * 1024;            // [0,2048)
    int lb = idx >> 7, j = idx & 127;
    if (j < 125)
      __builtin_nontemporal_store(oL[lb * 130 + j],
          &out[((size_t)(bh * 16 + lb) * 64 + (t + 1)) * 32000 + g * 125 + j]);
  }
  if (tid < 16) atomicMax(&amax[t * 32 + bh * 16 + tid], amaxL[tid]);
}

extern "C" void kernel_launch(void* const* d_in, const int* in_sizes, int n_in,
                              void* d_out, int out_size, void* d_ws, size_t ws_size,
                              hipStream_t stream) {
  (void)in_sizes; (void)n_in; (void)out_size; (void)ws_size;
  const int*   src     = (const int*)d_in[0];
  const int*   tgt     = (const int*)d_in[1];
  const float* enc_emb = (const float*)d_in[2];
  const float* dec_emb = (const float*)d_in[3];
  const float* ewih_f  = (const float*)d_in[4];
  const float* ewhh_f  = (const float*)d_in[5];
  const float* ebih_f  = (const float*)d_in[6];
  const float* ebhh_f  = (const float*)d_in[7];
  const float* ewih_r  = (const float*)d_in[8];
  const float* ewhh_r  = (const float*)d_in[9];
  const float* ebih_r  = (const float*)d_in[10];
  const float* ebhh_r  = (const float*)d_in[11];
  const float* dwih_f  = (const float*)d_in[12];
  const float* dwhh_f  = (const float*)d_in[13];
  const float* dbih_f  = (const float*)d_in[14];
  const float* dbhh_f  = (const float*)d_in[15];
  const float* dwih_r  = (const float*)d_in[16];
  const float* dwhh_r  = (const float*)d_in[17];
  const float* dbih_r  = (const float*)d_in[18];
  const float* dbhh_r  = (const float*)d_in[19];
  const float* cls_w   = (const float*)d_in[20];
  const float* cls_b   = (const float*)d_in[21];

  char* ws = (char*)d_ws;
  unsigned long long* amax = (unsigned long long*)(ws + OFF_AMAX);
  float* Xg                = (float*)(ws + OFF_XG);
  float* h_enc             = (float*)(ws + OFF_HENC);
  float* hcat              = (float*)(ws + OFF_HCAT);
  float* c_st              = (float*)(ws + OFF_CST);
  float* out               = (float*)d_out;

  // reset argmax slots (monotone atomicMax needs zeros each call)
  hipMemsetAsync(d_ws, 0, OFF_XG, stream);

  hipFuncSetAttribute((const void*)k_xg,
                      hipFuncAttributeMaxDynamicSharedMemorySize, LDS_ENC);
  hipFuncSetAttribute((const void*)k_enc,
                      hipFuncAttributeMaxDynamicSharedMemorySize, LDS_ENC);
  hipFuncSetAttribute((const void*)k_cell,
                      hipFuncAttributeMaxDynamicSharedMemorySize, LDS_CELL);
  hipFuncSetAttribute((const void*)k_cls,
                      hipFuncAttributeMaxDynamicSharedMemorySize, LDS_CLS);

  hipLaunchKernelGGL(k_xg, dim3(NBLK), dim3(NT), LDS_ENC, stream,
                     src, enc_emb, ewih_f, ebih_f, ebhh_f,
                     ewih_r, ebih_r, ebhh_r, Xg, h_enc, out);

  for (int s = 0; s < 128; ++s) {
    hipLaunchKernelGGL(k_enc, dim3(NBLK), dim3(NT), LDS_ENC, stream,
                       ewhh_f, ewhh_r, Xg, h_enc, hcat, c_st, s);
  }

  for (int t = 0; t < 63; ++t) {
    hipLaunchKernelGGL(k_cell, dim3(NBLK), dim3(NT), LDS_CELL, stream,
                       tgt, dec_emb,
                       dwih_f, dwhh_f, dbih_f, dbhh_f,
                       dwih_r, dwhh_r, dbih_r, dbhh_r,
                       hcat, c_st, amax, t);
    hipLaunchKernelGGL(k_cls, dim3(NBLK * 2), dim3(NT), LDS_CLS, stream,
                       cls_w, cls_b, hcat, amax, out, t);
  }
}

// Round 12
// 7396.259 us; speedup vs baseline: 2.7443x; 1.0360x over previous
//
#include <hip/hip_runtime.h>
#include <stdint.h>

// Seq2Seq (bi-LSTM encoder + greedy LSTM decoder), MI355X gfx950.
// v12: v11 with the __builtin_nontemporal_load type error fixed.
//   R11 failed to compile: __builtin_nontemporal_load requires a NATIVE
//   vector type (ext_vector_type), not HIP's float4 class. Weight loads now
//   use f32x4 (ext_vector_type(4)). Everything else identical to v11:
//   one block per row-group (125 rows x 32 b x full K), lane=(kc16 x bg4)
//   -> 256B distinct/instr NT w-loads; h LDS [32][257]f4 (b-stride-4 ->
//   2-way = free); 4 row-pair groups, acc[2][8]=16 regs; kc-butterfly
//   allreduce; in-register argmax across groups.
//
// B=32 S=128 T=64 V=32000 E=512 H=512 (4H=2048 gates per cell)

#define NT 1024
#define NBLK 256

constexpr int HSTR = 580;    // enc h-stage LDS row stride (512 + pad, %32==4)
constexpr int XSTR = 1156;   // dec [x|h]-stage stride (1024 + pad, %32==4)
constexpr unsigned LDS_ENC = 78336;    // (32*580 + 512 + 512) floats
constexpr unsigned LDS_CELL = 150016;  // (32*1156 + 512) floats
constexpr unsigned LDS_CLS = 147968;   // cH[32][257]f4 + oL[32][126] + amaxL[32]

// workspace layout (bytes)
constexpr size_t OFF_AMAX  = 0;                     // 63*32 u64 = 16128
constexpr size_t OFF_XG    = 17408;                 // 256*128*32*16 f32 = 67108864
constexpr size_t OFF_HENC  = OFF_XG + 67108864ULL;  // 2buf*2dir*32*512 f32 = 262144
constexpr size_t OFF_HCAT  = OFF_HENC + 262144ULL;  // 2buf*32*1024 f32 = 262144
constexpr size_t OFF_CST   = OFF_HCAT + 262144ULL;  // 2dir*32*512 f32 = 131072

typedef float f32x4 __attribute__((ext_vector_type(4)));

__device__ __forceinline__ float sigm(float x) {
  if (x >= 0.f) return 1.f / (1.f + expf(-x));
  float e = expf(x);
  return e / (1.f + e);
}

__device__ __forceinline__ void fma4(const float4& w, const float4& h, float4& a) {
  a.x = fmaf(w.x, h.x, a.x);
  a.y = fmaf(w.y, h.y, a.y);
  a.z = fmaf(w.z, h.z, a.z);
  a.w = fmaf(w.w, h.w, a.w);
}

__device__ __forceinline__ float hsum4(const float4& a) {
  return (a.x + a.y) + (a.z + a.w);
}

__device__ __forceinline__ float dot4(const float4& w, const float4& h, float acc) {
  return fmaf(w.x, h.x, fmaf(w.y, h.y, fmaf(w.z, h.z, fmaf(w.w, h.w, acc))));
}

__device__ __forceinline__ float dot4v(const f32x4& w, const float4& h, float acc) {
  return fmaf(w.x, h.x, fmaf(w.y, h.y, fmaf(w.z, h.z, fmaf(w.w, h.w, acc))));
}

__device__ __forceinline__ unsigned long long lgkey(float lg, int vr) {
  unsigned u = __float_as_uint(lg);
  u = (u & 0x80000000u) ? ~u : (u | 0x80000000u);
  return ((unsigned long long)u << 32) | (0xFFFFFFFFu - (unsigned)vr);
}

// ---------------- K0: Xg = emb(src) @ wih^T + bih + bhh; init h_enc, out ----
__global__ __launch_bounds__(NT) void k_xg(
    const int* __restrict__ src, const float* __restrict__ enc_emb,
    const float* __restrict__ ewih_f, const float* __restrict__ ebih_f,
    const float* __restrict__ ebhh_f,
    const float* __restrict__ ewih_r, const float* __restrict__ ebih_r,
    const float* __restrict__ ebhh_r,
    float* __restrict__ Xg, float* __restrict__ h_enc, float* __restrict__ out) {
  extern __shared__ float smem[];
  const int tid = threadIdx.x;
  const int bid = blockIdx.x;
  const int d  = bid >> 7;
  const int u0 = (bid & 127) << 2;

  float* hL  = smem;               // [32][HSTR]

  const int rgE = tid >> 7;
  const int bpE = (tid >> 4) & 7;
  const int ksE = tid & 15;
  const int r0E = rgE * 2, r1E = r0E + 1;
  const int growE0 = (r0E & 3) * 512 + u0 + (r0E >> 2);
  const int growE1 = (r1E & 3) * 512 + u0 + (r1E >> 2);

  const float* ewih = d ? ewih_r : ewih_f;
  const float* ebih = d ? ebih_r : ebih_f;
  const float* ebhh = d ? ebhh_r : ebhh_f;

  float4 wA[8], wB[8];
#pragma unroll
  for (int i4 = 0; i4 < 8; ++i4) {
    wA[i4] = *(const float4*)(ewih + (size_t)growE0 * 512 + ksE * 32 + i4 * 4);
    wB[i4] = *(const float4*)(ewih + (size_t)growE1 * 512 + ksE * 32 + i4 * 4);
  }
  const float biasA = ebih[growE0] + ebhh[growE0];
  const float biasB = ebih[growE1] + ebhh[growE1];

  for (int t = 0; t < 128; ++t) {
    {
      int b = tid >> 5, i = tid & 31;
      int tok = src[b * 128 + t];
      const float* row = enc_emb + (size_t)tok * 512;
#pragma unroll
      for (int q = 0; q < 4; ++q) {
        int k = (i + 32 * q) * 4;
        float4 v = *(const float4*)(row + k);
        int pc = k + ((k >> 5) << 2);
        *(float4*)(hL + b * HSTR + pc) = v;
      }
    }
    __syncthreads();
    for (int gi = 0; gi < 4; ++gi) {
      int b = bpE * 4 + gi;
      const float* hb = hL + b * HSTR + ksE * 36;
      float4 a0 = {0, 0, 0, 0}, a1 = {0, 0, 0, 0};
#pragma unroll
      for (int i4 = 0; i4 < 8; ++i4) {
        float4 h4 = *(const float4*)(hb + i4 * 4);
        fma4(wA[i4], h4, a0);
        fma4(wB[i4], h4, a1);
      }
      float s0 = hsum4(a0), s1 = hsum4(a1);
#pragma unroll
      for (int m = 1; m <= 8; m <<= 1) {
        s0 += __shfl_xor(s0, m, 64);
        s1 += __shfl_xor(s1, m, 64);
      }
      if (ksE == 0) {
        float* xgp = Xg + ((size_t)bid << 16) + t * 512 + b * 16;
        xgp[r0E] = s0 + biasA;
        xgp[r1E] = s1 + biasB;
      }
    }
    __syncthreads();
  }

  if (tid < 128) {
    int b = tid & 31, j = tid >> 5;
    h_enc[((0 * 2 + d) * 32 + b) * 512 + u0 + j] = 0.f;
  }
  for (int i = tid; i < 4000; i += NT) {
    int b = i & 31, vv = i >> 5;  // vv < 125
    __builtin_nontemporal_store(0.f,
        &out[(size_t)b * 64 * 32000 + bid * 125 + vv]);
  }
}

// ---------------- K_enc: one bi-LSTM encoder time step ----------------
__global__ __launch_bounds__(NT) void k_enc(
    const float* __restrict__ ewhh_f, const float* __restrict__ ewhh_r,
    const float* __restrict__ Xg, float* __restrict__ h_enc,
    float* __restrict__ hcat, float* __restrict__ c_st, int s) {
  extern __shared__ float smem[];
  const int tid = threadIdx.x;
  const int bid = blockIdx.x;
  const int d  = bid >> 7;
  const int u0 = (bid & 127) << 2;
  const int cur = s & 1;
  const int td = d ? (127 - s) : s;

  float* hL  = smem;               // [32][HSTR]
  float* XgL = smem + 32 * HSTR;   // [32*16]
  float* gL  = XgL + 512;          // [32*16]

  const int rgE = tid >> 7;
  const int bpE = (tid >> 4) & 7;
  const int ksE = tid & 15;
  const int r0E = rgE * 2, r1E = r0E + 1;
  const int growE0 = (r0E & 3) * 512 + u0 + (r0E >> 2);
  const int growE1 = (r1E & 3) * 512 + u0 + (r1E >> 2);

  const float* ewhh = d ? ewhh_r : ewhh_f;

  float4 wA[8], wB[8];
#pragma unroll
  for (int i4 = 0; i4 < 8; ++i4) {
    wA[i4] = *(const float4*)(ewhh + (size_t)growE0 * 512 + ksE * 32 + i4 * 4);
    wB[i4] = *(const float4*)(ewhh + (size_t)growE1 * 512 + ksE * 32 + i4 * 4);
  }

  {
    int b = tid >> 5, i = tid & 31;
    const float* hr = h_enc + ((size_t)(cur * 2 + d) * 32 + b) * 512;
#pragma unroll
    for (int q = 0; q < 4; ++q) {
      int k = (i + 32 * q) * 4;
      float4 v = *(const float4*)(hr + k);
      int pc = k + ((k >> 5) << 2);
      *(float4*)(hL + b * HSTR + pc) = v;
    }
    if (tid < 128) {
      ((float4*)XgL)[tid] =
          *(const float4*)(Xg + ((size_t)bid << 16) + td * 512 + tid * 4);
    }
  }
  __syncthreads();
  for (int gi = 0; gi < 4; ++gi) {
    int b = bpE * 4 + gi;
    const float* hb = hL + b * HSTR + ksE * 36;
    float4 a0 = {0, 0, 0, 0}, a1 = {0, 0, 0, 0};
#pragma unroll
    for (int i4 = 0; i4 < 8; ++i4) {
      float4 h4 = *(const float4*)(hb + i4 * 4);
      fma4(wA[i4], h4, a0);
      fma4(wB[i4], h4, a1);
    }
    float s0 = hsum4(a0), s1 = hsum4(a1);
#pragma unroll
    for (int m = 1; m <= 8; m <<= 1) {
      s0 += __shfl_xor(s0, m, 64);
      s1 += __shfl_xor(s1, m, 64);
    }
    if (ksE == 0) {
      gL[b * 16 + r0E] = s0 + XgL[b * 16 + r0E];
      gL[b * 16 + r1E] = s1 + XgL[b * 16 + r1E];
    }
  }
  __syncthreads();
  if (tid < 128) {
    int b = tid & 31, j = tid >> 5;
    float g_i = gL[b * 16 + (j << 2) + 0];
    float g_f = gL[b * 16 + (j << 2) + 1];
    float g_g = gL[b * 16 + (j << 2) + 2];
    float g_o = gL[b * 16 + (j << 2) + 3];
    float c = (s == 0) ? 0.f : c_st[(d * 32 + b) * 512 + u0 + j];
    c = sigm(g_f) * c + sigm(g_i) * tanhf(g_g);
    float h = sigm(g_o) * tanhf(c);
    c_st[(d * 32 + b) * 512 + u0 + j] = c;
    h_enc[(((cur ^ 1) * 2 + d) * 32 + b) * 512 + u0 + j] = h;
    if (s == 127) hcat[b * 1024 + d * 512 + u0 + j] = h;  // buf 0
  }
}

// ---------------- K_cell: one decoder LSTM step (both dirs) ----------------
__global__ __launch_bounds__(NT) void k_cell(
    const int* __restrict__ tgt, const float* __restrict__ dec_emb,
    const float* __restrict__ dwih_f, const float* __restrict__ dwhh_f,
    const float* __restrict__ dbih_f, const float* __restrict__ dbhh_f,
    const float* __restrict__ dwih_r, const float* __restrict__ dwhh_r,
    const float* __restrict__ dbih_r, const float* __restrict__ dbhh_r,
    float* __restrict__ hcat, float* __restrict__ c_st,
    const unsigned long long* __restrict__ amax, int t) {
  extern __shared__ float smem[];
  const int tid = threadIdx.x;
  const int bid = blockIdx.x;
  const int d  = bid >> 7;
  const int u0 = (bid & 127) << 2;
  const int p = t & 1;

  float* xhL = smem;               // [32][XSTR]
  float* gLd = smem + 32 * XSTR;   // [32*16]

  const int rgD = tid >> 7;
  const int bpD = (tid >> 5) & 3;
  const int ksD = tid & 31;
  const int r0D = rgD * 2, r1D = r0D + 1;
  const int growD0 = (r0D & 3) * 512 + u0 + (r0D >> 2);
  const int growD1 = (r1D & 3) * 512 + u0 + (r1D >> 2);

  const float* dwih = d ? dwih_r : dwih_f;
  const float* dwhh = d ? dwhh_r : dwhh_f;
  const float* dbih = d ? dbih_r : dbih_f;
  const float* dbhh = d ? dbhh_r : dbhh_f;

  {
    int b = tid >> 5, i = tid & 31;
    int tok;
    if (t == 0) {
      tok = tgt[b * 64];
    } else {
      unsigned long long kv = amax[(t - 1) * 32 + b];
      tok = (int)(0xFFFFFFFFu - (unsigned)(kv & 0xFFFFFFFFull));
    }
    const float* xr = dec_emb + (size_t)tok * 512;
    const float* hr = hcat + (size_t)p * 32768 + b * 1024 + d * 512;
#pragma unroll
    for (int q = 0; q < 4; ++q) {
      int k = (i + 32 * q) * 4;
      float4 v = *(const float4*)(xr + k);
      int pc = k + ((k >> 5) << 2);
      *(float4*)(xhL + b * XSTR + pc) = v;
    }
#pragma unroll
    for (int q = 0; q < 4; ++q) {
      int k = (i + 32 * q) * 4;
      float4 v = *(const float4*)(hr + k);
      int c2 = 512 + k;
      int pc = c2 + ((c2 >> 5) << 2);
      *(float4*)(xhL + b * XSTR + pc) = v;
    }
  }
  float4 wA[8], wB[8];
  {
    const float* s0p = (ksD < 16) ? (dwih + (size_t)growD0 * 512 + ksD * 32)
                                  : (dwhh + (size_t)growD0 * 512 + (ksD - 16) * 32);
    const float* s1p = (ksD < 16) ? (dwih + (size_t)growD1 * 512 + ksD * 32)
                                  : (dwhh + (size_t)growD1 * 512 + (ksD - 16) * 32);
#pragma unroll
    for (int i4 = 0; i4 < 8; ++i4) {
      wA[i4] = *(const float4*)(s0p + i4 * 4);
      wB[i4] = *(const float4*)(s1p + i4 * 4);
    }
  }
  const float biasA = dbih[growD0] + dbhh[growD0];
  const float biasB = dbih[growD1] + dbhh[growD1];
  __syncthreads();
  for (int gi = 0; gi < 8; ++gi) {
    int b = bpD * 8 + gi;
    const float* hb = xhL + b * XSTR + ksD * 36;
    float4 a0 = {0, 0, 0, 0}, a1 = {0, 0, 0, 0};
#pragma unroll
    for (int i4 = 0; i4 < 8; ++i4) {
      float4 h4 = *(const float4*)(hb + i4 * 4);
      fma4(wA[i4], h4, a0);
      fma4(wB[i4], h4, a1);
    }
    float s0 = hsum4(a0), s1 = hsum4(a1);
#pragma unroll
    for (int m = 1; m <= 16; m <<= 1) {
      s0 += __shfl_xor(s0, m, 64);
      s1 += __shfl_xor(s1, m, 64);
    }
    if (ksD == 0) {
      gLd[b * 16 + r0D] = s0 + biasA;
      gLd[b * 16 + r1D] = s1 + biasB;
    }
  }
  __syncthreads();
  if (tid < 128) {
    int b = tid & 31, j = tid >> 5;
    float g_i = gLd[b * 16 + (j << 2) + 0];
    float g_f = gLd[b * 16 + (j << 2) + 1];
    float g_g = gLd[b * 16 + (j << 2) + 2];
    float g_o = gLd[b * 16 + (j << 2) + 3];
    float c = c_st[(d * 32 + b) * 512 + u0 + j];
    c = sigm(g_f) * c + sigm(g_i) * tanhf(g_g);
    float h = sigm(g_o) * tanhf(c);
    c_st[(d * 32 + b) * 512 + u0 + j] = c;
    hcat[(size_t)(p ^ 1) * 32768 + b * 1024 + d * 512 + u0 + j] = h;
  }
}

// ---------------- K_cls v12: duplication-free, 256B-coalesced ----------------
// grid 256 (one block per row-group: 125 rows x 32 b x full K).
// lane = (kc[0,16) x bg[0,4)): w-loads 256B distinct/instr (NT); lane's
// batches b = bg + 4j (stride-4 -> h LDS reads 2-way = free). Wave owns 8
// rows as 4 sequential pairs; acc[2][8]=16 regs; kc-butterfly = allreduce.
__global__ __launch_bounds__(NT) void k_cls(
    const float* __restrict__ cls_w, const float* __restrict__ cls_b,
    const float* __restrict__ hcat, unsigned long long* __restrict__ amax,
    float* __restrict__ out, int t) {
  extern __shared__ float smem[];
  const int tid = threadIdx.x;
  const int g = blockIdx.x;
  const int p = t & 1;

  // LDS: cH float4[32][257] floats [0,32896); oL [32][126] floats [32896,36928);
  //      amaxL u64[32] at float 36928 (bytes 147712..147968)
  float* oL = smem + 32896;
  unsigned long long* amaxL = (unsigned long long*)(smem + 36928);

  {  // stage full h into padded cH; zero amaxL
    const float4* hr4 = (const float4*)(hcat + (size_t)(p ^ 1) * 32768);
    float4* cH4w = (float4*)smem;
#pragma unroll
    for (int q = 0; q < 8; ++q) {
      int f = tid + q * 1024;        // [0,8192)
      int b = f >> 8, k4 = f & 255;
      cH4w[b * 257 + k4] = hr4[f];
    }
    if (tid < 32) amaxL[tid] = 0ull;
  }
  __syncthreads();
  {
    const int lane = tid & 63;
    const int widu = __builtin_amdgcn_readfirstlane(tid >> 6);
    const int kc = lane & 15;         // k-chunk [0,16): 256B coalesced w-loads
    const int bg = lane >> 4;         // batch-class [0,4): b = bg + 4j
    const float4* cH4 = (const float4*)smem;

    unsigned long long bk[8];
#pragma unroll
    for (int j = 0; j < 8; ++j) bk[j] = 0ull;

#pragma unroll
    for (int g2 = 0; g2 < 4; ++g2) {
      const int lrA = widu * 8 + g2 * 2;   // up to 126
      const int lrB = lrA + 1;             // up to 127
      const int lrAc = lrA > 124 ? 124 : lrA;
      const int lrBc = lrB > 124 ? 124 : lrB;
      const float* wra = cls_w + (size_t)(g * 125 + lrAc) * 1024;
      const float* wrb = cls_w + (size_t)(g * 125 + lrBc) * 1024;

      float accA[8], accB[8];
#pragma unroll
      for (int j = 0; j < 8; ++j) { accA[j] = 0.f; accB[j] = 0.f; }

#pragma unroll 2
      for (int q = 0; q < 16; ++q) {
        const int ko = q * 64 + kc * 4;
        f32x4 wa = __builtin_nontemporal_load((const f32x4*)(wra + ko));
        f32x4 wb = __builtin_nontemporal_load((const f32x4*)(wrb + ko));
#pragma unroll
        for (int j = 0; j < 8; ++j) {
          float4 h4 = cH4[(bg + 4 * j) * 257 + q * 16 + kc];
          accA[j] = dot4v(wa, h4, accA[j]);
          accB[j] = dot4v(wb, h4, accB[j]);
        }
      }

      // butterfly over the 16 kc lanes = allreduce (every lane gets full sums)
#pragma unroll
      for (int j = 0; j < 8; ++j) {
#pragma unroll
        for (int m = 1; m <= 8; m <<= 1) {
          accA[j] += __shfl_xor(accA[j], m, 64);
          accB[j] += __shfl_xor(accB[j], m, 64);
        }
      }

      const int vrA = g * 125 + lrAc;
      const int vrB = g * 125 + lrBc;
      const float cbA = cls_b[vrA];
      const float cbB = cls_b[vrB];
#pragma unroll
      for (int j = 0; j < 8; ++j) {
        const int b = bg + 4 * j;
        const float lgA = accA[j] + cbA;
        const float lgB = accB[j] + cbB;
        if (kc == 0 && lrA < 125) oL[b * 126 + lrA] = lgA;
        if (kc == 1 && lrB < 125) oL[b * 126 + lrB] = lgB;
        if (lrA < 125) {
          unsigned long long kA = lgkey(lgA, vrA);
          bk[j] = kA > bk[j] ? kA : bk[j];
        }
        if (lrB < 125) {
          unsigned long long kB = lgkey(lgB, vrB);
          bk[j] = kB > bk[j] ? kB : bk[j];
        }
      }
    }
    if (kc == 0) {
#pragma unroll
      for (int j = 0; j < 8; ++j) atomicMax(&amaxL[bg + 4 * j], bk[j]);
    }
  }
  __syncthreads();
  // coalesced logit writeback (non-temporal) + global argmax merge
#pragma unroll
  for (int it = 0; it < 4; ++it) {
    int idx = tid + it * 1024;            // [0,4096)
    int b = idx >> 7, j = idx & 127;
    if (j < 125)
      __builtin_nontemporal_store(oL[b * 126 + j],
          &out[((size_t)b * 64 + (t + 1)) * 32000 + g * 125 + j]);
  }
  if (tid < 32) atomicMax(&amax[t * 32 + tid], amaxL[tid]);
}

extern "C" void kernel_launch(void* const* d_in, const int* in_sizes, int n_in,
                              void* d_out, int out_size, void* d_ws, size_t ws_size,
                              hipStream_t stream) {
  (void)in_sizes; (void)n_in; (void)out_size; (void)ws_size;
  const int*   src     = (const int*)d_in[0];
  const int*   tgt     = (const int*)d_in[1];
  const float* enc_emb = (const float*)d_in[2];
  const float* dec_emb = (const float*)d_in[3];
  const float* ewih_f  = (const float*)d_in[4];
  const float* ewhh_f  = (const float*)d_in[5];
  const float* ebih_f  = (const float*)d_in[6];
  const float* ebhh_f  = (const float*)d_in[7];
  const float* ewih_r  = (const float*)d_in[8];
  const float* ewhh_r  = (const float*)d_in[9];
  const float* ebih_r  = (const float*)d_in[10];
  const float* ebhh_r  = (const float*)d_in[11];
  const float* dwih_f  = (const float*)d_in[12];
  const float* dwhh_f  = (const float*)d_in[13];
  const float* dbih_f  = (const float*)d_in[14];
  const float* dbhh_f  = (const float*)d_in[15];
  const float* dwih_r  = (const float*)d_in[16];
  const float* dwhh_r  = (const float*)d_in[17];
  const float* dbih_r  = (const float*)d_in[18];
  const float* dbhh_r  = (const float*)d_in[19];
  const float* cls_w   = (const float*)d_in[20];
  const float* cls_b   = (const float*)d_in[21];

  char* ws = (char*)d_ws;
  unsigned long long* amax = (unsigned long long*)(ws + OFF_AMAX);
  float* Xg                = (float*)(ws + OFF_XG);
  float* h_enc             = (float*)(ws + OFF_HENC);
  float* hcat              = (float*)(ws + OFF_HCAT);
  float* c_st              = (float*)(ws + OFF_CST);
  float* out               = (float*)d_out;

  // reset argmax slots (monotone atomicMax needs zeros each call)
  hipMemsetAsync(d_ws, 0, OFF_XG, stream);

  hipFuncSetAttribute((const void*)k_xg,
                      hipFuncAttributeMaxDynamicSharedMemorySize, LDS_ENC);
  hipFuncSetAttribute((const void*)k_enc,
                      hipFuncAttributeMaxDynamicSharedMemorySize, LDS_ENC);
  hipFuncSetAttribute((const void*)k_cell,
                      hipFuncAttributeMaxDynamicSharedMemorySize, LDS_CELL);
  hipFuncSetAttribute((const void*)k_cls,
                      hipFuncAttributeMaxDynamicSharedMemorySize, LDS_CLS);

  hipLaunchKernelGGL(k_xg, dim3(NBLK), dim3(NT), LDS_ENC, stream,
                     src, enc_emb, ewih_f, ebih_f, ebhh_f,
                     ewih_r, ebih_r, ebhh_r, Xg, h_enc, out);

  for (int s = 0; s < 128; ++s) {
    hipLaunchKernelGGL(k_enc, dim3(NBLK), dim3(NT), LDS_ENC, stream,
                       ewhh_f, ewhh_r, Xg, h_enc, hcat, c_st, s);
  }

  for (int t = 0; t < 63; ++t) {
    hipLaunchKernelGGL(k_cell, dim3(NBLK), dim3(NT), LDS_CELL, stream,
                       tgt, dec_emb,
                       dwih_f, dwhh_f, dbih_f, dbhh_f,
                       dwih_r, dwhh_r, dbih_r, dbhh_r,
                       hcat, c_st, amax, t);
    hipLaunchKernelGGL(k_cls, dim3(NBLK), dim3(NT), LDS_CLS, stream,
                       cls_w, cls_b, hcat, amax, out, t);
  }
}

// Round 13
// 7087.463 us; speedup vs baseline: 2.8639x; 1.0436x over previous
//
#include <hip/hip_runtime.h>
#include <stdint.h>

// Seq2Seq (bi-LSTM encoder + greedy LSTM decoder), MI355X gfx950.
// v13: k_cls retiled kc8/bg8, 2 passes — balance LDS vs VMEM.
//   R12 analysis (no rocprof; analytic): v12's 4 full-h LDS re-reads/wave =
//   8192 b128/block = ~41us on the shared LDS pipe > HBM ~25us. The acc<=16
//   budget forces rows/pass x b/lane = 16; kc_width = 2 x b/lane; passes =
//   b/lane/2. Balanced point kc8/bg8: 128B-coalesced w-loads AND 2 passes
//   (LDS ~20us), VALU 13.6us, HBM ~25us -> k_cls ~30us (from ~45).
//   Everything else identical to v12.
//
// B=32 S=128 T=64 V=32000 E=512 H=512 (4H=2048 gates per cell)

#define NT 1024
#define NBLK 256

constexpr int HSTR = 580;    // enc h-stage LDS row stride (512 + pad, %32==4)
constexpr int XSTR = 1156;   // dec [x|h]-stage stride (1024 + pad, %32==4)
constexpr unsigned LDS_ENC = 78336;    // (32*580 + 512 + 512) floats
constexpr unsigned LDS_CELL = 150016;  // (32*1156 + 512) floats
constexpr unsigned LDS_CLS = 147968;   // cH[32][257]f4 + oL[32][126] + amaxL[32]

// workspace layout (bytes)
constexpr size_t OFF_AMAX  = 0;                     // 63*32 u64 = 16128
constexpr size_t OFF_XG    = 17408;                 // 256*128*32*16 f32 = 67108864
constexpr size_t OFF_HENC  = OFF_XG + 67108864ULL;  // 2buf*2dir*32*512 f32 = 262144
constexpr size_t OFF_HCAT  = OFF_HENC + 262144ULL;  // 2buf*32*1024 f32 = 262144
constexpr size_t OFF_CST   = OFF_HCAT + 262144ULL;  // 2dir*32*512 f32 = 131072

typedef float f32x4 __attribute__((ext_vector_type(4)));

__device__ __forceinline__ float sigm(float x) {
  if (x >= 0.f) return 1.f / (1.f + expf(-x));
  float e = expf(x);
  return e / (1.f + e);
}

__device__ __forceinline__ void fma4(const float4& w, const float4& h, float4& a) {
  a.x = fmaf(w.x, h.x, a.x);
  a.y = fmaf(w.y, h.y, a.y);
  a.z = fmaf(w.z, h.z, a.z);
  a.w = fmaf(w.w, h.w, a.w);
}

__device__ __forceinline__ float hsum4(const float4& a) {
  return (a.x + a.y) + (a.z + a.w);
}

__device__ __forceinline__ float dot4(const float4& w, const float4& h, float acc) {
  return fmaf(w.x, h.x, fmaf(w.y, h.y, fmaf(w.z, h.z, fmaf(w.w, h.w, acc))));
}

__device__ __forceinline__ float dot4v(const f32x4& w, const float4& h, float acc) {
  return fmaf(w.x, h.x, fmaf(w.y, h.y, fmaf(w.z, h.z, fmaf(w.w, h.w, acc))));
}

__device__ __forceinline__ unsigned long long lgkey(float lg, int vr) {
  unsigned u = __float_as_uint(lg);
  u = (u & 0x80000000u) ? ~u : (u | 0x80000000u);
  return ((unsigned long long)u << 32) | (0xFFFFFFFFu - (unsigned)vr);
}

// ---------------- K0: Xg = emb(src) @ wih^T + bih + bhh; init h_enc, out ----
__global__ __launch_bounds__(NT) void k_xg(
    const int* __restrict__ src, const float* __restrict__ enc_emb,
    const float* __restrict__ ewih_f, const float* __restrict__ ebih_f,
    const float* __restrict__ ebhh_f,
    const float* __restrict__ ewih_r, const float* __restrict__ ebih_r,
    const float* __restrict__ ebhh_r,
    float* __restrict__ Xg, float* __restrict__ h_enc, float* __restrict__ out) {
  extern __shared__ float smem[];
  const int tid = threadIdx.x;
  const int bid = blockIdx.x;
  const int d  = bid >> 7;
  const int u0 = (bid & 127) << 2;

  float* hL  = smem;               // [32][HSTR]

  const int rgE = tid >> 7;
  const int bpE = (tid >> 4) & 7;
  const int ksE = tid & 15;
  const int r0E = rgE * 2, r1E = r0E + 1;
  const int growE0 = (r0E & 3) * 512 + u0 + (r0E >> 2);
  const int growE1 = (r1E & 3) * 512 + u0 + (r1E >> 2);

  const float* ewih = d ? ewih_r : ewih_f;
  const float* ebih = d ? ebih_r : ebih_f;
  const float* ebhh = d ? ebhh_r : ebhh_f;

  float4 wA[8], wB[8];
#pragma unroll
  for (int i4 = 0; i4 < 8; ++i4) {
    wA[i4] = *(const float4*)(ewih + (size_t)growE0 * 512 + ksE * 32 + i4 * 4);
    wB[i4] = *(const float4*)(ewih + (size_t)growE1 * 512 + ksE * 32 + i4 * 4);
  }
  const float biasA = ebih[growE0] + ebhh[growE0];
  const float biasB = ebih[growE1] + ebhh[growE1];

  for (int t = 0; t < 128; ++t) {
    {
      int b = tid >> 5, i = tid & 31;
      int tok = src[b * 128 + t];
      const float* row = enc_emb + (size_t)tok * 512;
#pragma unroll
      for (int q = 0; q < 4; ++q) {
        int k = (i + 32 * q) * 4;
        float4 v = *(const float4*)(row + k);
        int pc = k + ((k >> 5) << 2);
        *(float4*)(hL + b * HSTR + pc) = v;
      }
    }
    __syncthreads();
    for (int gi = 0; gi < 4; ++gi) {
      int b = bpE * 4 + gi;
      const float* hb = hL + b * HSTR + ksE * 36;
      float4 a0 = {0, 0, 0, 0}, a1 = {0, 0, 0, 0};
#pragma unroll
      for (int i4 = 0; i4 < 8; ++i4) {
        float4 h4 = *(const float4*)(hb + i4 * 4);
        fma4(wA[i4], h4, a0);
        fma4(wB[i4], h4, a1);
      }
      float s0 = hsum4(a0), s1 = hsum4(a1);
#pragma unroll
      for (int m = 1; m <= 8; m <<= 1) {
        s0 += __shfl_xor(s0, m, 64);
        s1 += __shfl_xor(s1, m, 64);
      }
      if (ksE == 0) {
        float* xgp = Xg + ((size_t)bid << 16) + t * 512 + b * 16;
        xgp[r0E] = s0 + biasA;
        xgp[r1E] = s1 + biasB;
      }
    }
    __syncthreads();
  }

  if (tid < 128) {
    int b = tid & 31, j = tid >> 5;
    h_enc[((0 * 2 + d) * 32 + b) * 512 + u0 + j] = 0.f;
  }
  for (int i = tid; i < 4000; i += NT) {
    int b = i & 31, vv = i >> 5;  // vv < 125
    __builtin_nontemporal_store(0.f,
        &out[(size_t)b * 64 * 32000 + bid * 125 + vv]);
  }
}

// ---------------- K_enc: one bi-LSTM encoder time step ----------------
__global__ __launch_bounds__(NT) void k_enc(
    const float* __restrict__ ewhh_f, const float* __restrict__ ewhh_r,
    const float* __restrict__ Xg, float* __restrict__ h_enc,
    float* __restrict__ hcat, float* __restrict__ c_st, int s) {
  extern __shared__ float smem[];
  const int tid = threadIdx.x;
  const int bid = blockIdx.x;
  const int d  = bid >> 7;
  const int u0 = (bid & 127) << 2;
  const int cur = s & 1;
  const int td = d ? (127 - s) : s;

  float* hL  = smem;               // [32][HSTR]
  float* XgL = smem + 32 * HSTR;   // [32*16]
  float* gL  = XgL + 512;          // [32*16]

  const int rgE = tid >> 7;
  const int bpE = (tid >> 4) & 7;
  const int ksE = tid & 15;
  const int r0E = rgE * 2, r1E = r0E + 1;
  const int growE0 = (r0E & 3) * 512 + u0 + (r0E >> 2);
  const int growE1 = (r1E & 3) * 512 + u0 + (r1E >> 2);

  const float* ewhh = d ? ewhh_r : ewhh_f;

  float4 wA[8], wB[8];
#pragma unroll
  for (int i4 = 0; i4 < 8; ++i4) {
    wA[i4] = *(const float4*)(ewhh + (size_t)growE0 * 512 + ksE * 32 + i4 * 4);
    wB[i4] = *(const float4*)(ewhh + (size_t)growE1 * 512 + ksE * 32 + i4 * 4);
  }

  {
    int b = tid >> 5, i = tid & 31;
    const float* hr = h_enc + ((size_t)(cur * 2 + d) * 32 + b) * 512;
#pragma unroll
    for (int q = 0; q < 4; ++q) {
      int k = (i + 32 * q) * 4;
      float4 v = *(const float4*)(hr + k);
      int pc = k + ((k >> 5) << 2);
      *(float4*)(hL + b * HSTR + pc) = v;
    }
    if (tid < 128) {
      ((float4*)XgL)[tid] =
          *(const float4*)(Xg + ((size_t)bid << 16) + td * 512 + tid * 4);
    }
  }
  __syncthreads();
  for (int gi = 0; gi < 4; ++gi) {
    int b = bpE * 4 + gi;
    const float* hb = hL + b * HSTR + ksE * 36;
    float4 a0 = {0, 0, 0, 0}, a1 = {0, 0, 0, 0};
#pragma unroll
    for (int i4 = 0; i4 < 8; ++i4) {
      float4 h4 = *(const float4*)(hb + i4 * 4);
      fma4(wA[i4], h4, a0);
      fma4(wB[i4], h4, a1);
    }
    float s0 = hsum4(a0), s1 = hsum4(a1);
#pragma unroll
    for (int m = 1; m <= 8; m <<= 1) {
      s0 += __shfl_xor(s0, m, 64);
      s1 += __shfl_xor(s1, m, 64);
    }
    if (ksE == 0) {
      gL[b * 16 + r0E] = s0 + XgL[b * 16 + r0E];
      gL[b * 16 + r1E] = s1 + XgL[b * 16 + r1E];
    }
  }
  __syncthreads();
  if (tid < 128) {
    int b = tid & 31, j = tid >> 5;
    float g_i = gL[b * 16 + (j << 2) + 0];
    float g_f = gL[b * 16 + (j << 2) + 1];
    float g_g = gL[b * 16 + (j << 2) + 2];
    float g_o = gL[b * 16 + (j << 2) + 3];
    float c = (s == 0) ? 0.f : c_st[(d * 32 + b) * 512 + u0 + j];
    c = sigm(g_f) * c + sigm(g_i) * tanhf(g_g);
    float h = sigm(g_o) * tanhf(c);
    c_st[(d * 32 + b) * 512 + u0 + j] = c;
    h_enc[(((cur ^ 1) * 2 + d) * 32 + b) * 512 + u0 + j] = h;
    if (s == 127) hcat[b * 1024 + d * 512 + u0 + j] = h;  // buf 0
  }
}

// ---------------- K_cell: one decoder LSTM step (both dirs) ----------------
__global__ __launch_bounds__(NT) void k_cell(
    const int* __restrict__ tgt, const float* __restrict__ dec_emb,
    const float* __restrict__ dwih_f, const float* __restrict__ dwhh_f,
    const float* __restrict__ dbih_f, const float* __restrict__ dbhh_f,
    const float* __restrict__ dwih_r, const float* __restrict__ dwhh_r,
    const float* __restrict__ dbih_r, const float* __restrict__ dbhh_r,
    float* __restrict__ hcat, float* __restrict__ c_st,
    const unsigned long long* __restrict__ amax, int t) {
  extern __shared__ float smem[];
  const int tid = threadIdx.x;
  const int bid = blockIdx.x;
  const int d  = bid >> 7;
  const int u0 = (bid & 127) << 2;
  const int p = t & 1;

  float* xhL = smem;               // [32][XSTR]
  float* gLd = smem + 32 * XSTR;   // [32*16]

  const int rgD = tid >> 7;
  const int bpD = (tid >> 5) & 3;
  const int ksD = tid & 31;
  const int r0D = rgD * 2, r1D = r0D + 1;
  const int growD0 = (r0D & 3) * 512 + u0 + (r0D >> 2);
  const int growD1 = (r1D & 3) * 512 + u0 + (r1D >> 2);

  const float* dwih = d ? dwih_r : dwih_f;
  const float* dwhh = d ? dwhh_r : dwhh_f;
  const float* dbih = d ? dbih_r : dbih_f;
  const float* dbhh = d ? dbhh_r : dbhh_f;

  {
    int b = tid >> 5, i = tid & 31;
    int tok;
    if (t == 0) {
      tok = tgt[b * 64];
    } else {
      unsigned long long kv = amax[(t - 1) * 32 + b];
      tok = (int)(0xFFFFFFFFu - (unsigned)(kv & 0xFFFFFFFFull));
    }
    const float* xr = dec_emb + (size_t)tok * 512;
    const float* hr = hcat + (size_t)p * 32768 + b * 1024 + d * 512;
#pragma unroll
    for (int q = 0; q < 4; ++q) {
      int k = (i + 32 * q) * 4;
      float4 v = *(const float4*)(xr + k);
      int pc = k + ((k >> 5) << 2);
      *(float4*)(xhL + b * XSTR + pc) = v;
    }
#pragma unroll
    for (int q = 0; q < 4; ++q) {
      int k = (i + 32 * q) * 4;
      float4 v = *(const float4*)(hr + k);
      int c2 = 512 + k;
      int pc = c2 + ((c2 >> 5) << 2);
      *(float4*)(xhL + b * XSTR + pc) = v;
    }
  }
  float4 wA[8], wB[8];
  {
    const float* s0p = (ksD < 16) ? (dwih + (size_t)growD0 * 512 + ksD * 32)
                                  : (dwhh + (size_t)growD0 * 512 + (ksD - 16) * 32);
    const float* s1p = (ksD < 16) ? (dwih + (size_t)growD1 * 512 + ksD * 32)
                                  : (dwhh + (size_t)growD1 * 512 + (ksD - 16) * 32);
#pragma unroll
    for (int i4 = 0; i4 < 8; ++i4) {
      wA[i4] = *(const float4*)(s0p + i4 * 4);
      wB[i4] = *(const float4*)(s1p + i4 * 4);
    }
  }
  const float biasA = dbih[growD0] + dbhh[growD0];
  const float biasB = dbih[growD1] + dbhh[growD1];
  __syncthreads();
  for (int gi = 0; gi < 8; ++gi) {
    int b = bpD * 8 + gi;
    const float* hb = xhL + b * XSTR + ksD * 36;
    float4 a0 = {0, 0, 0, 0}, a1 = {0, 0, 0, 0};
#pragma unroll
    for (int i4 = 0; i4 < 8; ++i4) {
      float4 h4 = *(const float4*)(hb + i4 * 4);
      fma4(wA[i4], h4, a0);
      fma4(wB[i4], h4, a1);
    }
    float s0 = hsum4(a0), s1 = hsum4(a1);
#pragma unroll
    for (int m = 1; m <= 16; m <<= 1) {
      s0 += __shfl_xor(s0, m, 64);
      s1 += __shfl_xor(s1, m, 64);
    }
    if (ksD == 0) {
      gLd[b * 16 + r0D] = s0 + biasA;
      gLd[b * 16 + r1D] = s1 + biasB;
    }
  }
  __syncthreads();
  if (tid < 128) {
    int b = tid & 31, j = tid >> 5;
    float g_i = gLd[b * 16 + (j << 2) + 0];
    float g_f = gLd[b * 16 + (j << 2) + 1];
    float g_g = gLd[b * 16 + (j << 2) + 2];
    float g_o = gLd[b * 16 + (j << 2) + 3];
    float c = c_st[(d * 32 + b) * 512 + u0 + j];
    c = sigm(g_f) * c + sigm(g_i) * tanhf(g_g);
    float h = sigm(g_o) * tanhf(c);
    c_st[(d * 32 + b) * 512 + u0 + j] = c;
    hcat[(size_t)(p ^ 1) * 32768 + b * 1024 + d * 512 + u0 + j] = h;
  }
}

// ---------------- K_cls v13: kc8/bg8, 2 passes ----------------
// grid 256 (one block per row-group: 125 rows x 32 b x full K).
// lane = (kc[0,8) x bg[0,8)): w-loads 128B distinct/instr (NT); lane's
// batches b = bg + 8j (j<4). Wave owns 8 rows as 2 passes of 4 rows;
// acc[4r][4j]=16 regs; kc-butterfly(1,2,4) = allreduce; writer lane kc==r.
__global__ __launch_bounds__(NT) void k_cls(
    const float* __restrict__ cls_w, const float* __restrict__ cls_b,
    const float* __restrict__ hcat, unsigned long long* __restrict__ amax,
    float* __restrict__ out, int t) {
  extern __shared__ float smem[];
  const int tid = threadIdx.x;
  const int g = blockIdx.x;
  const int p = t & 1;

  // LDS: cH float4[32][257] floats [0,32896); oL [32][126] floats [32896,36928);
  //      amaxL u64[32] at float 36928 (bytes 147712..147968)
  float* oL = smem + 32896;
  unsigned long long* amaxL = (unsigned long long*)(smem + 36928);

  {  // stage full h into padded cH; zero amaxL
    const float4* hr4 = (const float4*)(hcat + (size_t)(p ^ 1) * 32768);
    float4* cH4w = (float4*)smem;
#pragma unroll
    for (int q = 0; q < 8; ++q) {
      int f = tid + q * 1024;        // [0,8192)
      int b = f >> 8, k4 = f & 255;
      cH4w[b * 257 + k4] = hr4[f];
    }
    if (tid < 32) amaxL[tid] = 0ull;
  }
  __syncthreads();
  {
    const int lane = tid & 63;
    const int widu = __builtin_amdgcn_readfirstlane(tid >> 6);
    const int kc = lane & 7;          // k-chunk [0,8): 128B coalesced w-loads
    const int bg = lane >> 3;         // batch-class [0,8): b = bg + 8j
    const float4* cH4 = (const float4*)smem;

    unsigned long long bk[4];
#pragma unroll
    for (int j = 0; j < 4; ++j) bk[j] = 0ull;

#pragma unroll
    for (int pass = 0; pass < 2; ++pass) {
      const int lr0 = widu * 8 + pass * 4;   // rows lr0..lr0+3 (up to 127)
      const float* wr0 = cls_w + (size_t)(g * 125 + (lr0 + 0 > 124 ? 124 : lr0 + 0)) * 1024;
      const float* wr1 = cls_w + (size_t)(g * 125 + (lr0 + 1 > 124 ? 124 : lr0 + 1)) * 1024;
      const float* wr2 = cls_w + (size_t)(g * 125 + (lr0 + 2 > 124 ? 124 : lr0 + 2)) * 1024;
      const float* wr3 = cls_w + (size_t)(g * 125 + (lr0 + 3 > 124 ? 124 : lr0 + 3)) * 1024;

      float acc[16];   // acc[r*4 + j]
#pragma unroll
      for (int i = 0; i < 16; ++i) acc[i] = 0.f;

#pragma unroll 2
      for (int q = 0; q < 32; ++q) {
        const int ko = q * 32 + kc * 4;      // 8 kc lanes cover 128B contiguous
        f32x4 w0 = __builtin_nontemporal_load((const f32x4*)(wr0 + ko));
        f32x4 w1 = __builtin_nontemporal_load((const f32x4*)(wr1 + ko));
        f32x4 w2 = __builtin_nontemporal_load((const f32x4*)(wr2 + ko));
        f32x4 w3 = __builtin_nontemporal_load((const f32x4*)(wr3 + ko));
#pragma unroll
        for (int j = 0; j < 4; ++j) {
          float4 h4 = cH4[(bg + 8 * j) * 257 + q * 8 + kc];
          acc[0 * 4 + j] = dot4v(w0, h4, acc[0 * 4 + j]);
          acc[1 * 4 + j] = dot4v(w1, h4, acc[1 * 4 + j]);
          acc[2 * 4 + j] = dot4v(w2, h4, acc[2 * 4 + j]);
          acc[3 * 4 + j] = dot4v(w3, h4, acc[3 * 4 + j]);
        }
      }

      // butterfly over the 8 kc lanes = allreduce (every lane gets full sums)
#pragma unroll
      for (int i = 0; i < 16; ++i) {
        acc[i] += __shfl_xor(acc[i], 1, 64);
        acc[i] += __shfl_xor(acc[i], 2, 64);
        acc[i] += __shfl_xor(acc[i], 4, 64);
      }

#pragma unroll
      for (int r = 0; r < 4; ++r) {
        const int lr = lr0 + r;
        const int lrc = lr > 124 ? 124 : lr;
        const int vr = g * 125 + lrc;
        const float cb = cls_b[vr];
#pragma unroll
        for (int j = 0; j < 4; ++j) {
          const float lg = acc[r * 4 + j] + cb;
          const int b = bg + 8 * j;
          if (kc == r && lr < 125) oL[b * 126 + lr] = lg;
          if (lr < 125) {
            unsigned long long k = lgkey(lg, vr);
            bk[j] = k > bk[j] ? k : bk[j];
          }
        }
      }
    }
    if (kc == 0) {
#pragma unroll
      for (int j = 0; j < 4; ++j) atomicMax(&amaxL[bg + 8 * j], bk[j]);
    }
  }
  __syncthreads();
  // coalesced logit writeback (non-temporal) + global argmax merge
#pragma unroll
  for (int it = 0; it < 4; ++it) {
    int idx = tid + it * 1024;            // [0,4096)
    int b = idx >> 7, j = idx & 127;
    if (j < 125)
      __builtin_nontemporal_store(oL[b * 126 + j],
          &out[((size_t)b * 64 + (t + 1)) * 32000 + g * 125 + j]);
  }
  if (tid < 32) atomicMax(&amax[t * 32 + tid], amaxL[tid]);
}

extern "C" void kernel_launch(void* const* d_in, const int* in_sizes, int n_in,
                              void* d_out, int out_size, void* d_ws, size_t ws_size,
                              hipStream_t stream) {
  (void)in_sizes; (void)n_in; (void)out_size; (void)ws_size;
  const int*   src     = (const int*)d_in[0];
  const int*   tgt     = (const int*)d_in[1];
  const float* enc_emb = (const float*)d_in[2];
  const float* dec_emb = (const float*)d_in[3];
  const float* ewih_f  = (const float*)d_in[4];
  const float* ewhh_f  = (const float*)d_in[5];
  const float* ebih_f  = (const float*)d_in[6];
  const float* ebhh_f  = (const float*)d_in[7];
  const float* ewih_r  = (const float*)d_in[8];
  const float* ewhh_r  = (const float*)d_in[9];
  const float* ebih_r  = (const float*)d_in[10];
  const float* ebhh_r  = (const float*)d_in[11];
  const float* dwih_f  = (const float*)d_in[12];
  const float* dwhh_f  = (const float*)d_in[13];
  const float* dbih_f  = (const float*)d_in[14];
  const float* dbhh_f  = (const float*)d_in[15];
  const float* dwih_r  = (const float*)d_in[16];
  const float* dwhh_r  = (const float*)d_in[17];
  const float* dbih_r  = (const float*)d_in[18];
  const float* dbhh_r  = (const float*)d_in[19];
  const float* cls_w   = (const float*)d_in[20];
  const float* cls_b   = (const float*)d_in[21];

  char* ws = (char*)d_ws;
  unsigned long long* amax = (unsigned long long*)(ws + OFF_AMAX);
  float* Xg                = (float*)(ws + OFF_XG);
  float* h_enc             = (float*)(ws + OFF_HENC);
  float* hcat              = (float*)(ws + OFF_HCAT);
  float* c_st              = (float*)(ws + OFF_CST);
  float* out               = (float*)d_out;

  // reset argmax slots (monotone atomicMax needs zeros each call)
  hipMemsetAsync(d_ws, 0, OFF_XG, stream);

  hipFuncSetAttribute((const void*)k_xg,
                      hipFuncAttributeMaxDynamicSharedMemorySize, LDS_ENC);
  hipFuncSetAttribute((const void*)k_enc,
                      hipFuncAttributeMaxDynamicSharedMemorySize, LDS_ENC);
  hipFuncSetAttribute((const void*)k_cell,
                      hipFuncAttributeMaxDynamicSharedMemorySize, LDS_CELL);
  hipFuncSetAttribute((const void*)k_cls,
                      hipFuncAttributeMaxDynamicSharedMemorySize, LDS_CLS);

  hipLaunchKernelGGL(k_xg, dim3(NBLK), dim3(NT), LDS_ENC, stream,
                     src, enc_emb, ewih_f, ebih_f, ebhh_f,
                     ewih_r, ebih_r, ebhh_r, Xg, h_enc, out);

  for (int s = 0; s < 128; ++s) {
    hipLaunchKernelGGL(k_enc, dim3(NBLK), dim3(NT), LDS_ENC, stream,
                       ewhh_f, ewhh_r, Xg, h_enc, hcat, c_st, s);
  }

  for (int t = 0; t < 63; ++t) {
    hipLaunchKernelGGL(k_cell, dim3(NBLK), dim3(NT), LDS_CELL, stream,
                       tgt, dec_emb,
                       dwih_f, dwhh_f, dbih_f, dbhh_f,
                       dwih_r, dwhh_r, dbih_r, dbhh_r,
                       hcat, c_st, amax, t);
    hipLaunchKernelGGL(k_cls, dim3(NBLK), dim3(NT), LDS_CLS, stream,
                       cls_w, cls_b, hcat, amax, out, t);
  }
}